// Round 2
// baseline (1178.847 us; speedup 1.0000x reference)
//
#include <hip/hip_runtime.h>
#include <math.h>

#define N_USERS    100000
#define N_ENTITIES 200000
#define N_EDGES    1000000
#define NNZ        1000000
#define CDIM       64
#define N_FACTORS  4
#define N_REL      10
#define TEMP       0.2f

__device__ __forceinline__ float wave_sum64(float v) {
    #pragma unroll
    for (int m = 1; m < 64; m <<= 1) v += __shfl_xor(v, m, 64);
    return v;
}

// --- degree count + inverse --------------------------------------------------
__global__ __launch_bounds__(256) void count_kernel(const int* __restrict__ head,
                                                    float* __restrict__ cnt) {
    int i = blockIdx.x * blockDim.x + threadIdx.x;
    if (i < N_EDGES) atomicAdd(&cnt[head[i]], 1.0f);
}

__global__ __launch_bounds__(256) void inv_kernel(float* __restrict__ cnt) {
    int i = blockIdx.x * blockDim.x + threadIdx.x;
    if (i < N_ENTITIES) cnt[i] = 1.0f / fmaxf(cnt[i], 1.0f);
}

// --- disen_weight = softmax(att, axis=-1) @ weight  [F, C] (hop-invariant) ---
__global__ __launch_bounds__(256) void disen_kernel(const float* __restrict__ att,
                                                    const float* __restrict__ weight,
                                                    float* __restrict__ dw) {
    int tid = threadIdx.x;            // 256 threads: f = tid>>6, c = tid&63
    int f = tid >> 6, c = tid & 63;
    float m = -1e30f;
    for (int r = 0; r < N_REL; ++r) m = fmaxf(m, att[f * N_REL + r]);
    float e[N_REL], s = 0.0f;
    for (int r = 0; r < N_REL; ++r) { e[r] = expf(att[f * N_REL + r] - m); s += e[r]; }
    float acc = 0.0f;
    for (int r = 0; r < N_REL; ++r) acc += (e[r] / s) * weight[r * CDIM + c];
    dw[f * CDIM + c] = acc;
}

// --- cor = mutual information scalar ----------------------------------------
__global__ void cor_kernel(const float* __restrict__ att, float* __restrict__ out) {
    if (threadIdx.x != 0 || blockIdx.x != 0) return;
    float rowsum[N_FACTORS];
    for (int f = 0; f < N_FACTORS; ++f) {
        float s = 0.0f;
        for (int j = 0; j < N_REL; ++j) s += att[f * N_REL + j];
        rowsum[f] = s;
    }
    float cor = 0.0f;
    for (int i = 0; i < N_REL; ++i) {
        float nsq = 0.0f, ttl = 0.0f;
        for (int f = 0; f < N_FACTORS; ++f) {
            float a = att[f * N_REL + i];
            nsq += a * a;
            ttl += a * rowsum[f];
        }
        float n = sqrtf(nsq);
        float pos = 0.0f;
        for (int f = 0; f < N_FACTORS; ++f) {
            float a = att[f * N_REL + i] / n;
            pos += a * a;
        }
        cor += (ttl - pos) / TEMP;   // == -log(exp(pos/T)/exp(ttl/T))
    }
    *out = cor;
}

// --- KG aggregate: scatter-add neigh = ecur[tail]*weight[rel] into eagg[head]
__global__ __launch_bounds__(256) void kg_agg_kernel(const float* __restrict__ ecur,
                                                     const float* __restrict__ weight,
                                                     const int* __restrict__ head,
                                                     const int* __restrict__ tail,
                                                     const int* __restrict__ etype,
                                                     float* __restrict__ eagg) {
    int gid = blockIdx.x * blockDim.x + threadIdx.x;
    int wid = gid >> 6;
    int lane = gid & 63;
    if (wid >= N_EDGES) return;
    int h = head[wid];
    int t = tail[wid];
    int r = etype[wid] - 1;
    float v = ecur[(size_t)t * CDIM + lane] * weight[r * CDIM + lane];
    atomicAdd(&eagg[(size_t)h * CDIM + lane], v);
}

// --- sparse user aggregate: uagg[row] += val * ecur[col] ---------------------
__global__ __launch_bounds__(256) void user_agg_kernel(const float* __restrict__ ecur,
                                                       const int* __restrict__ rows,
                                                       const int* __restrict__ cols,
                                                       const float* __restrict__ vals,
                                                       float* __restrict__ uagg) {
    int gid = blockIdx.x * blockDim.x + threadIdx.x;
    int wid = gid >> 6;
    int lane = gid & 63;
    if (wid >= NNZ) return;
    int u = rows[wid];
    int e = cols[wid];
    float v = vals[wid] * ecur[(size_t)e * CDIM + lane];
    atomicAdd(&uagg[(size_t)u * CDIM + lane], v);
}

// --- entity update: mean, l2norm, write ecur, accumulate eres ---------------
__global__ __launch_bounds__(256) void entity_update_kernel(const float* __restrict__ eagg,
                                                            const float* __restrict__ inv,
                                                            float* __restrict__ ecur,
                                                            float* __restrict__ eres) {
    int gid = blockIdx.x * blockDim.x + threadIdx.x;
    int wid = gid >> 6;
    int lane = gid & 63;
    if (wid >= N_ENTITIES) return;
    float v = eagg[(size_t)wid * CDIM + lane] * inv[wid];
    float s = wave_sum64(v * v);
    float n = fmaxf(sqrtf(s), 1e-12f);
    float o = v / n;
    ecur[(size_t)wid * CDIM + lane] = o;
    eres[(size_t)wid * CDIM + lane] += o;
}

// --- user update: factor attention, blend, l2norm, accumulate ---------------
__global__ __launch_bounds__(256) void user_update_kernel(const float* __restrict__ latent,
                                                          const float* __restrict__ dw,
                                                          const float* __restrict__ uagg,
                                                          float* __restrict__ ucur,
                                                          float* __restrict__ ures) {
    int gid = blockIdx.x * blockDim.x + threadIdx.x;
    int wid = gid >> 6;
    int lane = gid & 63;
    if (wid >= N_USERS) return;
    float ue = ucur[(size_t)wid * CDIM + lane];
    float d0 = wave_sum64(ue * latent[0 * CDIM + lane]);
    float d1 = wave_sum64(ue * latent[1 * CDIM + lane]);
    float d2 = wave_sum64(ue * latent[2 * CDIM + lane]);
    float d3 = wave_sum64(ue * latent[3 * CDIM + lane]);
    float m = fmaxf(fmaxf(d0, d1), fmaxf(d2, d3));
    float e0 = expf(d0 - m), e1 = expf(d1 - m), e2 = expf(d2 - m), e3 = expf(d3 - m);
    float ssum = e0 + e1 + e2 + e3;
    float g = (e0 * dw[0 * CDIM + lane] + e1 * dw[1 * CDIM + lane] +
               e2 * dw[2 * CDIM + lane] + e3 * dw[3 * CDIM + lane]) / ssum;
    float ua = uagg[(size_t)wid * CDIM + lane] * (1.0f + g);
    float s = wave_sum64(ua * ua);
    float n = fmaxf(sqrtf(s), 1e-12f);
    float o = ua / n;
    ucur[(size_t)wid * CDIM + lane] = o;
    ures[(size_t)wid * CDIM + lane] += o;
}

extern "C" void kernel_launch(void* const* d_in, const int* in_sizes, int n_in,
                              void* d_out, int out_size, void* d_ws, size_t ws_size,
                              hipStream_t stream) {
    const float* user_emb   = (const float*)d_in[0];
    const float* entity_emb = (const float*)d_in[1];
    const float* latent_emb = (const float*)d_in[2];
    const float* weight     = (const float*)d_in[3];
    const float* att        = (const float*)d_in[4];
    const int*   edge_index = (const int*)d_in[5];
    const int*   edge_type  = (const int*)d_in[6];
    const int*   inter_rows = (const int*)d_in[7];
    const int*   inter_cols = (const int*)d_in[8];
    const float* inter_vals = (const float*)d_in[9];

    float* eres = (float*)d_out;                           // [N_ENTITIES, C]
    float* ures = eres + (size_t)N_ENTITIES * CDIM;        // [N_USERS, C]
    float* cor  = ures + (size_t)N_USERS * CDIM;           // [1]

    char* ws = (char*)d_ws;
    float* ecur = (float*)ws; ws += sizeof(float) * (size_t)N_ENTITIES * CDIM;
    float* eagg = (float*)ws; ws += sizeof(float) * (size_t)N_ENTITIES * CDIM;
    float* ucur = (float*)ws; ws += sizeof(float) * (size_t)N_USERS * CDIM;
    float* uagg = (float*)ws; ws += sizeof(float) * (size_t)N_USERS * CDIM;
    float* invc = (float*)ws; ws += sizeof(float) * (size_t)N_ENTITIES;
    float* dw   = (float*)ws; ws += sizeof(float) * N_FACTORS * CDIM;

    const int* head = edge_index;               // edge_index[0, :]
    const int* tail = edge_index + N_EDGES;     // edge_index[1, :]

    // init: res = emb (copies), cur = emb, degree count
    (void)hipMemcpyAsync(ecur, entity_emb, sizeof(float) * (size_t)N_ENTITIES * CDIM,
                         hipMemcpyDeviceToDevice, stream);
    (void)hipMemcpyAsync(ucur, user_emb, sizeof(float) * (size_t)N_USERS * CDIM,
                         hipMemcpyDeviceToDevice, stream);
    (void)hipMemcpyAsync(eres, entity_emb, sizeof(float) * (size_t)N_ENTITIES * CDIM,
                         hipMemcpyDeviceToDevice, stream);
    (void)hipMemcpyAsync(ures, user_emb, sizeof(float) * (size_t)N_USERS * CDIM,
                         hipMemcpyDeviceToDevice, stream);
    (void)hipMemsetAsync(invc, 0, sizeof(float) * N_ENTITIES, stream);

    count_kernel<<<(N_EDGES + 255) / 256, 256, 0, stream>>>(head, invc);
    inv_kernel<<<(N_ENTITIES + 255) / 256, 256, 0, stream>>>(invc);
    disen_kernel<<<1, 256, 0, stream>>>(att, weight, dw);
    cor_kernel<<<1, 64, 0, stream>>>(att, cor);

    const int agg_grid_e = (int)(((size_t)N_EDGES * 64 + 255) / 256);
    const int agg_grid_u = (int)(((size_t)NNZ * 64 + 255) / 256);
    const int upd_grid_e = (int)(((size_t)N_ENTITIES * 64 + 255) / 256);
    const int upd_grid_u = (int)(((size_t)N_USERS * 64 + 255) / 256);

    for (int hop = 0; hop < 2; ++hop) {
        (void)hipMemsetAsync(eagg, 0, sizeof(float) * (size_t)N_ENTITIES * CDIM, stream);
        (void)hipMemsetAsync(uagg, 0, sizeof(float) * (size_t)N_USERS * CDIM, stream);
        kg_agg_kernel<<<agg_grid_e, 256, 0, stream>>>(ecur, weight, head, tail,
                                                      edge_type, eagg);
        user_agg_kernel<<<agg_grid_u, 256, 0, stream>>>(ecur, inter_rows, inter_cols,
                                                        inter_vals, uagg);
        entity_update_kernel<<<upd_grid_e, 256, 0, stream>>>(eagg, invc, ecur, eres);
        user_update_kernel<<<upd_grid_u, 256, 0, stream>>>(latent_emb, dw, uagg, ucur, ures);
    }
}

// Round 4
// 750.034 us; speedup vs baseline: 1.5717x; 1.5717x over previous
//
#include <hip/hip_runtime.h>
#include <math.h>

#define N_USERS    100000
#define N_ENTITIES 200000
#define N_EDGES    1000000
#define NNZ        1000000
#define CDIM       64
#define N_FACTORS  4
#define N_REL      10
#define TEMP       0.2f
#define SCAN_CHUNK 2048   // elems per block in the 3-phase exclusive scan

__device__ __forceinline__ float wave_sum64(float v) {
    #pragma unroll
    for (int m = 1; m < 64; m <<= 1) v += __shfl_xor(v, m, 64);
    return v;
}

// --- histogram --------------------------------------------------------------
__global__ __launch_bounds__(256) void hist_kernel(const int* __restrict__ idx, int n,
                                                   int* __restrict__ cnt) {
    int i = blockIdx.x * 256 + threadIdx.x;
    if (i < n) atomicAdd(&cnt[idx[i]], 1);
}

// --- 3-phase exclusive scan of cnt[n] -> off[0..n]  -------------------------
__global__ __launch_bounds__(256) void scan_p1(const int* __restrict__ cnt, int n,
                                               int* __restrict__ bsum) {
    __shared__ int s[256];
    int b = blockIdx.x, t = threadIdx.x;
    int base = b * SCAN_CHUNK;
    int acc = 0;
    for (int k = t; k < SCAN_CHUNK; k += 256) {
        int i = base + k;
        if (i < n) acc += cnt[i];
    }
    s[t] = acc; __syncthreads();
    for (int d = 128; d > 0; d >>= 1) { if (t < d) s[t] += s[t + d]; __syncthreads(); }
    if (t == 0) bsum[b] = s[0];
}

__global__ void scan_p2(int* bsum, int nb, int* off_n) {
    if (threadIdx.x || blockIdx.x) return;
    int run = 0;
    for (int b = 0; b < nb; ++b) { int v = bsum[b]; bsum[b] = run; run += v; }
    *off_n = run;
}

__global__ __launch_bounds__(256) void scan_p3(const int* __restrict__ cnt, int n,
                                               const int* __restrict__ bsum,
                                               int* __restrict__ off) {
    __shared__ int s[256];
    int b = blockIdx.x, t = threadIdx.x;
    int base = b * SCAN_CHUNK + t * 8;
    int v[8]; int acc = 0;
    #pragma unroll
    for (int k = 0; k < 8; ++k) { int i = base + k; v[k] = (i < n) ? cnt[i] : 0; acc += v[k]; }
    s[t] = acc; __syncthreads();
    for (int d = 1; d < 256; d <<= 1) {
        int x = (t >= d) ? s[t - d] : 0;
        __syncthreads();
        s[t] += x;
        __syncthreads();
    }
    int excl = s[t] - acc + bsum[b];
    #pragma unroll
    for (int k = 0; k < 8; ++k) { int i = base + k; if (i < n) { off[i] = excl; excl += v[k]; } }
}

// --- CSR scatter ------------------------------------------------------------
__global__ __launch_bounds__(256) void edge_scatter(const int* __restrict__ head,
                                                    const int* __restrict__ tail,
                                                    const int* __restrict__ etype,
                                                    int* __restrict__ cursor,
                                                    int* __restrict__ epk) {
    int i = blockIdx.x * 256 + threadIdx.x;
    if (i >= N_EDGES) return;
    int h = head[i];
    int pos = atomicAdd(&cursor[h], 1);
    epk[pos] = tail[i] | ((etype[i] - 1) << 20);   // tail<2^18, rel<16
}

__global__ __launch_bounds__(256) void inter_scatter(const int* __restrict__ rows,
                                                     const int* __restrict__ cols,
                                                     const float* __restrict__ vals,
                                                     int* __restrict__ cursor,
                                                     int* __restrict__ ucol,
                                                     float* __restrict__ uval) {
    int i = blockIdx.x * 256 + threadIdx.x;
    if (i >= NNZ) return;
    int r = rows[i];
    int pos = atomicAdd(&cursor[r], 1);
    ucol[pos] = cols[i];
    uval[pos] = vals[i];
}

// --- disen_weight = softmax(att, axis=-1) @ weight  [F, C] ------------------
__global__ __launch_bounds__(256) void disen_kernel(const float* __restrict__ att,
                                                    const float* __restrict__ weight,
                                                    float* __restrict__ dw) {
    int tid = threadIdx.x;
    int f = tid >> 6, c = tid & 63;
    float m = -1e30f;
    for (int r = 0; r < N_REL; ++r) m = fmaxf(m, att[f * N_REL + r]);
    float e[N_REL], s = 0.0f;
    for (int r = 0; r < N_REL; ++r) { e[r] = expf(att[f * N_REL + r] - m); s += e[r]; }
    float acc = 0.0f;
    for (int r = 0; r < N_REL; ++r) acc += (e[r] / s) * weight[r * CDIM + c];
    dw[f * CDIM + c] = acc;
}

// --- cor scalar -------------------------------------------------------------
__global__ void cor_kernel(const float* __restrict__ att, float* __restrict__ out) {
    if (threadIdx.x != 0 || blockIdx.x != 0) return;
    float rowsum[N_FACTORS];
    for (int f = 0; f < N_FACTORS; ++f) {
        float s = 0.0f;
        for (int j = 0; j < N_REL; ++j) s += att[f * N_REL + j];
        rowsum[f] = s;
    }
    float cor = 0.0f;
    for (int i = 0; i < N_REL; ++i) {
        float nsq = 0.0f, ttl = 0.0f;
        for (int f = 0; f < N_FACTORS; ++f) {
            float a = att[f * N_REL + i];
            nsq += a * a;
            ttl += a * rowsum[f];
        }
        float n = sqrtf(nsq);
        float pos = 0.0f;
        for (int f = 0; f < N_FACTORS; ++f) {
            float a = att[f * N_REL + i] / n;
            pos += a * a;
        }
        cor += (ttl - pos) / TEMP;
    }
    *out = cor;
}

// --- fused KG hop: gather + mean + l2norm + residual ------------------------
__global__ __launch_bounds__(256) void kg_fused(const float* __restrict__ eold,
                                                const int* __restrict__ eoff,
                                                const int* __restrict__ epk,
                                                const float* __restrict__ weight,
                                                const float* __restrict__ emb0,
                                                float* __restrict__ enew,   // may be null (last hop)
                                                float* __restrict__ eres,
                                                int first) {
    int gid = blockIdx.x * 256 + threadIdx.x;
    int h = gid >> 6, lane = gid & 63;
    if (h >= N_ENTITIES) return;
    int s = eoff[h], e = eoff[h + 1];
    float acc = 0.0f;
    for (int j = s; j < e; ++j) {
        int p = epk[j];
        int t = p & 0xFFFFF, r = p >> 20;
        acc += eold[(size_t)t * CDIM + lane] * weight[r * CDIM + lane];
    }
    float v = acc * (1.0f / fmaxf((float)(e - s), 1.0f));
    float ss = wave_sum64(v * v);
    float o = v / fmaxf(sqrtf(ss), 1e-12f);
    size_t oi = (size_t)h * CDIM + lane;
    if (enew) enew[oi] = o;
    eres[oi] = first ? (emb0[oi] + o) : (eres[oi] + o);
}

// --- fused user hop: gather + factor attention + l2norm + residual ----------
__global__ __launch_bounds__(256) void user_fused(const float* __restrict__ uold,
                                                  const float* __restrict__ eold,
                                                  const int* __restrict__ uoff,
                                                  const int* __restrict__ ucol,
                                                  const float* __restrict__ uval,
                                                  const float* __restrict__ latent,
                                                  const float* __restrict__ dw,
                                                  float* __restrict__ unew,  // may be null (last hop)
                                                  float* __restrict__ ures,
                                                  int first) {
    int gid = blockIdx.x * 256 + threadIdx.x;
    int u = gid >> 6, lane = gid & 63;
    if (u >= N_USERS) return;
    int s = uoff[u], e = uoff[u + 1];
    float acc = 0.0f;
    for (int j = s; j < e; ++j) {
        int c = ucol[j];
        acc += uval[j] * eold[(size_t)c * CDIM + lane];
    }
    float ue = uold[(size_t)u * CDIM + lane];
    float d0 = wave_sum64(ue * latent[0 * CDIM + lane]);
    float d1 = wave_sum64(ue * latent[1 * CDIM + lane]);
    float d2 = wave_sum64(ue * latent[2 * CDIM + lane]);
    float d3 = wave_sum64(ue * latent[3 * CDIM + lane]);
    float m = fmaxf(fmaxf(d0, d1), fmaxf(d2, d3));
    float e0 = expf(d0 - m), e1 = expf(d1 - m), e2 = expf(d2 - m), e3 = expf(d3 - m);
    float ssum = e0 + e1 + e2 + e3;
    float g = (e0 * dw[0 * CDIM + lane] + e1 * dw[1 * CDIM + lane] +
               e2 * dw[2 * CDIM + lane] + e3 * dw[3 * CDIM + lane]) / ssum;
    float ua = acc * (1.0f + g);
    float ss = wave_sum64(ua * ua);
    float o = ua / fmaxf(sqrtf(ss), 1e-12f);
    size_t oi = (size_t)u * CDIM + lane;
    if (unew) unew[oi] = o;
    ures[oi] = first ? (uold[oi] + o) : (ures[oi] + o);
}

extern "C" void kernel_launch(void* const* d_in, const int* in_sizes, int n_in,
                              void* d_out, int out_size, void* d_ws, size_t ws_size,
                              hipStream_t stream) {
    const float* user_emb   = (const float*)d_in[0];
    const float* entity_emb = (const float*)d_in[1];
    const float* latent_emb = (const float*)d_in[2];
    const float* weight     = (const float*)d_in[3];
    const float* att        = (const float*)d_in[4];
    const int*   edge_index = (const int*)d_in[5];
    const int*   edge_type  = (const int*)d_in[6];
    const int*   inter_rows = (const int*)d_in[7];
    const int*   inter_cols = (const int*)d_in[8];
    const float* inter_vals = (const float*)d_in[9];

    float* eres = (float*)d_out;                           // [N_ENTITIES, C]
    float* ures = eres + (size_t)N_ENTITIES * CDIM;        // [N_USERS, C]
    float* cor  = ures + (size_t)N_USERS * CDIM;           // [1]

    char* ws = (char*)d_ws;
    float* eA    = (float*)ws; ws += sizeof(float) * (size_t)N_ENTITIES * CDIM;
    float* uA    = (float*)ws; ws += sizeof(float) * (size_t)N_USERS * CDIM;
    int*   eoff  = (int*)ws;   ws += sizeof(int) * (N_ENTITIES + 1);
    int*   ecnt  = (int*)ws;   ws += sizeof(int) * N_ENTITIES;
    int*   ecur  = (int*)ws;   ws += sizeof(int) * N_ENTITIES;
    int*   epk   = (int*)ws;   ws += sizeof(int) * N_EDGES;
    int*   uoff  = (int*)ws;   ws += sizeof(int) * (N_USERS + 1);
    int*   ucnt  = (int*)ws;   ws += sizeof(int) * N_USERS;
    int*   ucur  = (int*)ws;   ws += sizeof(int) * N_USERS;
    int*   ucol  = (int*)ws;   ws += sizeof(int) * NNZ;
    float* uval  = (float*)ws; ws += sizeof(float) * NNZ;
    int*   ebsum = (int*)ws;   ws += sizeof(int) * 128;
    int*   ubsum = (int*)ws;   ws += sizeof(int) * 64;
    float* dw    = (float*)ws; ws += sizeof(float) * N_FACTORS * CDIM;

    const int* head = edge_index;               // edge_index[0, :]
    const int* tail = edge_index + N_EDGES;     // edge_index[1, :]

    const int NB_E = (N_ENTITIES + SCAN_CHUNK - 1) / SCAN_CHUNK;   // 98
    const int NB_U = (N_USERS + SCAN_CHUNK - 1) / SCAN_CHUNK;      // 49

    // --- CSR build ---
    (void)hipMemsetAsync(ecnt, 0, sizeof(int) * N_ENTITIES, stream);
    (void)hipMemsetAsync(ucnt, 0, sizeof(int) * N_USERS, stream);
    hist_kernel<<<(N_EDGES + 255) / 256, 256, 0, stream>>>(head, N_EDGES, ecnt);
    hist_kernel<<<(NNZ + 255) / 256, 256, 0, stream>>>(inter_rows, NNZ, ucnt);
    scan_p1<<<NB_E, 256, 0, stream>>>(ecnt, N_ENTITIES, ebsum);
    scan_p2<<<1, 64, 0, stream>>>(ebsum, NB_E, eoff + N_ENTITIES);
    scan_p3<<<NB_E, 256, 0, stream>>>(ecnt, N_ENTITIES, ebsum, eoff);
    scan_p1<<<NB_U, 256, 0, stream>>>(ucnt, N_USERS, ubsum);
    scan_p2<<<1, 64, 0, stream>>>(ubsum, NB_U, uoff + N_USERS);
    scan_p3<<<NB_U, 256, 0, stream>>>(ucnt, N_USERS, ubsum, uoff);
    (void)hipMemcpyAsync(ecur, eoff, sizeof(int) * N_ENTITIES, hipMemcpyDeviceToDevice, stream);
    (void)hipMemcpyAsync(ucur, uoff, sizeof(int) * N_USERS, hipMemcpyDeviceToDevice, stream);
    edge_scatter<<<(N_EDGES + 255) / 256, 256, 0, stream>>>(head, tail, edge_type, ecur, epk);
    inter_scatter<<<(NNZ + 255) / 256, 256, 0, stream>>>(inter_rows, inter_cols, inter_vals,
                                                         ucur, ucol, uval);

    // --- small precomputes ---
    disen_kernel<<<1, 256, 0, stream>>>(att, weight, dw);
    cor_kernel<<<1, 64, 0, stream>>>(att, cor);

    const int kg_grid   = (N_ENTITIES * 64) / 256;   // 50000
    const int user_grid = (N_USERS * 64) / 256;      // 25000

    // --- hop 0: read inputs directly, write eA/uA, res = emb + o ---
    kg_fused<<<kg_grid, 256, 0, stream>>>(entity_emb, eoff, epk, weight,
                                          entity_emb, eA, eres, 1);
    user_fused<<<user_grid, 256, 0, stream>>>(user_emb, entity_emb, uoff, ucol, uval,
                                              latent_emb, dw, uA, ures, 1);
    // --- hop 1: read eA/uA, skip new-emb write, res += o ---
    kg_fused<<<kg_grid, 256, 0, stream>>>(eA, eoff, epk, weight,
                                          entity_emb, (float*)nullptr, eres, 0);
    user_fused<<<user_grid, 256, 0, stream>>>(uA, eA, uoff, ucol, uval,
                                              latent_emb, dw, (float*)nullptr, ures, 0);
}

// Round 6
// 628.288 us; speedup vs baseline: 1.8763x; 1.1938x over previous
//
#include <hip/hip_runtime.h>
#include <math.h>

#define N_USERS    100000
#define N_ENTITIES 200000
#define N_EDGES    1000000
#define NNZ        1000000
#define CDIM       64
#define N_FACTORS  4
#define N_REL      10
#define TEMP       0.2f
#define SCAN_CHUNK 2048

typedef unsigned int u32;
typedef unsigned short u16;

__device__ __forceinline__ float bflo(u32 w) { return __uint_as_float(w << 16); }
__device__ __forceinline__ float bfhi(u32 w) { return __uint_as_float(w & 0xFFFF0000u); }
__device__ __forceinline__ u16 f2bf(float f) {
    u32 u = __float_as_uint(f);
    u32 r = u + 0x7FFFu + ((u >> 16) & 1u);   // RNE
    return (u16)(r >> 16);
}
__device__ __forceinline__ void unpack8(uint4 rv, float* x) {
    x[0] = bflo(rv.x); x[1] = bfhi(rv.x);
    x[2] = bflo(rv.y); x[3] = bfhi(rv.y);
    x[4] = bflo(rv.z); x[5] = bfhi(rv.z);
    x[6] = bflo(rv.w); x[7] = bfhi(rv.w);
}
__device__ __forceinline__ uint4 pack8(const float* x) {
    uint4 o;
    o.x = (u32)f2bf(x[0]) | ((u32)f2bf(x[1]) << 16);
    o.y = (u32)f2bf(x[2]) | ((u32)f2bf(x[3]) << 16);
    o.z = (u32)f2bf(x[4]) | ((u32)f2bf(x[5]) << 16);
    o.w = (u32)f2bf(x[6]) | ((u32)f2bf(x[7]) << 16);
    return o;
}

// --- f32 -> bf16 table conversion (8 elems/thread) --------------------------
__global__ __launch_bounds__(256) void cvt_bf16(const float* __restrict__ in,
                                                u16* __restrict__ out, int n8) {
    int i = blockIdx.x * 256 + threadIdx.x;
    if (i >= n8) return;
    const float4* p = (const float4*)(in + (size_t)i * 8);
    float4 a = p[0], b = p[1];
    float x[8] = {a.x, a.y, a.z, a.w, b.x, b.y, b.z, b.w};
    *(uint4*)(out + (size_t)i * 8) = pack8(x);
}

// --- histogram --------------------------------------------------------------
__global__ __launch_bounds__(256) void hist_kernel(const int* __restrict__ idx, int n,
                                                   int* __restrict__ cnt) {
    int i = blockIdx.x * 256 + threadIdx.x;
    if (i < n) atomicAdd(&cnt[idx[i]], 1);
}

// --- 3-phase exclusive scan -------------------------------------------------
__global__ __launch_bounds__(256) void scan_p1(const int* __restrict__ cnt, int n,
                                               int* __restrict__ bsum) {
    __shared__ int s[256];
    int b = blockIdx.x, t = threadIdx.x;
    int base = b * SCAN_CHUNK;
    int acc = 0;
    for (int k = t; k < SCAN_CHUNK; k += 256) {
        int i = base + k;
        if (i < n) acc += cnt[i];
    }
    s[t] = acc; __syncthreads();
    for (int d = 128; d > 0; d >>= 1) { if (t < d) s[t] += s[t + d]; __syncthreads(); }
    if (t == 0) bsum[b] = s[0];
}

__global__ void scan_p2(int* bsum, int nb, int* off_n) {
    if (threadIdx.x || blockIdx.x) return;
    int run = 0;
    for (int b = 0; b < nb; ++b) { int v = bsum[b]; bsum[b] = run; run += v; }
    *off_n = run;
}

__global__ __launch_bounds__(256) void scan_p3(const int* __restrict__ cnt, int n,
                                               const int* __restrict__ bsum,
                                               int* __restrict__ off) {
    __shared__ int s[256];
    int b = blockIdx.x, t = threadIdx.x;
    int base = b * SCAN_CHUNK + t * 8;
    int v[8]; int acc = 0;
    #pragma unroll
    for (int k = 0; k < 8; ++k) { int i = base + k; v[k] = (i < n) ? cnt[i] : 0; acc += v[k]; }
    s[t] = acc; __syncthreads();
    for (int d = 1; d < 256; d <<= 1) {
        int x = (t >= d) ? s[t - d] : 0;
        __syncthreads();
        s[t] += x;
        __syncthreads();
    }
    int excl = s[t] - acc + bsum[b];
    #pragma unroll
    for (int k = 0; k < 8; ++k) { int i = base + k; if (i < n) { off[i] = excl; excl += v[k]; } }
}

// --- CSR scatter ------------------------------------------------------------
__global__ __launch_bounds__(256) void edge_scatter(const int* __restrict__ head,
                                                    const int* __restrict__ tail,
                                                    const int* __restrict__ etype,
                                                    int* __restrict__ cursor,
                                                    int* __restrict__ epk) {
    int i = blockIdx.x * 256 + threadIdx.x;
    if (i >= N_EDGES) return;
    int h = head[i];
    int pos = atomicAdd(&cursor[h], 1);
    epk[pos] = tail[i] | ((etype[i] - 1) << 20);
}

__global__ __launch_bounds__(256) void inter_scatter(const int* __restrict__ rows,
                                                     const int* __restrict__ cols,
                                                     const float* __restrict__ vals,
                                                     int* __restrict__ cursor,
                                                     int* __restrict__ ucol,
                                                     float* __restrict__ uval) {
    int i = blockIdx.x * 256 + threadIdx.x;
    if (i >= NNZ) return;
    int r = rows[i];
    int pos = atomicAdd(&cursor[r], 1);
    ucol[pos] = cols[i];
    uval[pos] = vals[i];
}

// --- disen_weight = softmax(att, axis=-1) @ weight  [F, C] ------------------
__global__ __launch_bounds__(256) void disen_kernel(const float* __restrict__ att,
                                                    const float* __restrict__ weight,
                                                    float* __restrict__ dw) {
    int tid = threadIdx.x;
    int f = tid >> 6, c = tid & 63;
    float m = -1e30f;
    for (int r = 0; r < N_REL; ++r) m = fmaxf(m, att[f * N_REL + r]);
    float e[N_REL], s = 0.0f;
    for (int r = 0; r < N_REL; ++r) { e[r] = expf(att[f * N_REL + r] - m); s += e[r]; }
    float acc = 0.0f;
    for (int r = 0; r < N_REL; ++r) acc += (e[r] / s) * weight[r * CDIM + c];
    dw[f * CDIM + c] = acc;
}

// --- cor scalar -------------------------------------------------------------
__global__ void cor_kernel(const float* __restrict__ att, float* __restrict__ out) {
    if (threadIdx.x != 0 || blockIdx.x != 0) return;
    float rowsum[N_FACTORS];
    for (int f = 0; f < N_FACTORS; ++f) {
        float s = 0.0f;
        for (int j = 0; j < N_REL; ++j) s += att[f * N_REL + j];
        rowsum[f] = s;
    }
    float cor = 0.0f;
    for (int i = 0; i < N_REL; ++i) {
        float nsq = 0.0f, ttl = 0.0f;
        for (int f = 0; f < N_FACTORS; ++f) {
            float a = att[f * N_REL + i];
            nsq += a * a;
            ttl += a * rowsum[f];
        }
        float n = sqrtf(nsq);
        float pos = 0.0f;
        for (int f = 0; f < N_FACTORS; ++f) {
            float a = att[f * N_REL + i] / n;
            pos += a * a;
        }
        cor += (ttl - pos) / TEMP;
    }
    *out = cor;
}

// --- fused KG hop, 8 edges per wave-round -----------------------------------
// lane = eidx*8 + seg: eidx picks the edge, seg picks 8 channels.
__global__ __launch_bounds__(256) void kg_fused8(const u16* __restrict__ esrc,
                                                 const int* __restrict__ eoff,
                                                 const int* __restrict__ epk,
                                                 const float* __restrict__ weight,
                                                 const float* __restrict__ emb0,
                                                 u16* __restrict__ enew,
                                                 float* __restrict__ eres,
                                                 int last) {
    int gid = blockIdx.x * 256 + threadIdx.x;
    int h = gid >> 6;
    if (h >= N_ENTITIES) return;
    int lane = threadIdx.x & 63;
    int eidx = lane >> 3, seg = lane & 7;
    int s = eoff[h], e = eoff[h + 1];

    float acc[8];
    #pragma unroll
    for (int k = 0; k < 8; ++k) acc[k] = 0.0f;

    for (int jb = s; jb < e; jb += 8) {
        int j = jb + eidx;
        if (j < e) {
            int p = epk[j];
            int t = p & 0xFFFFF, r = p >> 20;
            uint4 rv = *(const uint4*)(esrc + (size_t)t * CDIM + seg * 8);
            float x[8]; unpack8(rv, x);
            const float4* wp = (const float4*)(weight + r * CDIM + seg * 8);
            float4 w0 = wp[0], w1 = wp[1];
            acc[0] += x[0] * w0.x; acc[1] += x[1] * w0.y;
            acc[2] += x[2] * w0.z; acc[3] += x[3] * w0.w;
            acc[4] += x[4] * w1.x; acc[5] += x[5] * w1.y;
            acc[6] += x[6] * w1.z; acc[7] += x[7] * w1.w;
        }
    }
    // reduce across the 8 edge-slots (lane bits 3..5)
    #pragma unroll
    for (int k = 0; k < 8; ++k) {
        acc[k] += __shfl_xor(acc[k], 8, 64);
        acc[k] += __shfl_xor(acc[k], 16, 64);
        acc[k] += __shfl_xor(acc[k], 32, 64);
    }
    float inv = 1.0f / fmaxf((float)(e - s), 1.0f);
    float ssq = 0.0f;
    #pragma unroll
    for (int k = 0; k < 8; ++k) { acc[k] *= inv; ssq += acc[k] * acc[k]; }
    ssq += __shfl_xor(ssq, 1, 64);
    ssq += __shfl_xor(ssq, 2, 64);
    ssq += __shfl_xor(ssq, 4, 64);
    float rn = 1.0f / fmaxf(sqrtf(ssq), 1e-12f);
    #pragma unroll
    for (int k = 0; k < 8; ++k) acc[k] *= rn;

    if (lane < 8) {   // seg == lane, one lane per 8-channel slice
        size_t base = (size_t)h * CDIM + lane * 8;
        if (!last) {
            *(uint4*)(enew + base) = pack8(acc);
        } else {
            // eres = emb0 + dequant(esrc[h]) + o   (esrc == hop0 output eA)
            uint4 pv = *(const uint4*)(esrc + base);
            float o0[8]; unpack8(pv, o0);
            float4 a = *(const float4*)(emb0 + base);
            float4 b = *(const float4*)(emb0 + base + 4);
            float4 r0, r1;
            r0.x = a.x + o0[0] + acc[0]; r0.y = a.y + o0[1] + acc[1];
            r0.z = a.z + o0[2] + acc[2]; r0.w = a.w + o0[3] + acc[3];
            r1.x = b.x + o0[4] + acc[4]; r1.y = b.y + o0[5] + acc[5];
            r1.z = b.z + o0[6] + acc[6]; r1.w = b.w + o0[7] + acc[7];
            *(float4*)(eres + base) = r0;
            *(float4*)(eres + base + 4) = r1;
        }
    }
}

// --- fused user hop, 8 nnz per wave-round -----------------------------------
__global__ __launch_bounds__(256) void user_fused8(const float* __restrict__ uoldf,
                                                   const u16* __restrict__ uoldb,
                                                   const u16* __restrict__ esrc,
                                                   const int* __restrict__ uoff,
                                                   const int* __restrict__ ucol,
                                                   const float* __restrict__ uval,
                                                   const float* __restrict__ latent,
                                                   const float* __restrict__ dw,
                                                   const float* __restrict__ uemb0,
                                                   u16* __restrict__ unew,
                                                   float* __restrict__ ures,
                                                   int last) {
    int gid = blockIdx.x * 256 + threadIdx.x;
    int u = gid >> 6;
    if (u >= N_USERS) return;
    int lane = threadIdx.x & 63;
    int eidx = lane >> 3, seg = lane & 7;
    int s = uoff[u], e = uoff[u + 1];

    float acc[8];
    #pragma unroll
    for (int k = 0; k < 8; ++k) acc[k] = 0.0f;

    for (int jb = s; jb < e; jb += 8) {
        int j = jb + eidx;
        if (j < e) {
            int c = ucol[j];
            float v = uval[j];
            uint4 rv = *(const uint4*)(esrc + (size_t)c * CDIM + seg * 8);
            float x[8]; unpack8(rv, x);
            #pragma unroll
            for (int k = 0; k < 8; ++k) acc[k] += v * x[k];
        }
    }
    #pragma unroll
    for (int k = 0; k < 8; ++k) {
        acc[k] += __shfl_xor(acc[k], 8, 64);
        acc[k] += __shfl_xor(acc[k], 16, 64);
        acc[k] += __shfl_xor(acc[k], 32, 64);
    }

    // current user row, channels seg*8..+8
    float uo[8];
    size_t ubase = (size_t)u * CDIM + seg * 8;
    if (uoldb) {
        uint4 pv = *(const uint4*)(uoldb + ubase);
        unpack8(pv, uo);
    } else {
        float4 a = *(const float4*)(uoldf + ubase);
        float4 b = *(const float4*)(uoldf + ubase + 4);
        uo[0] = a.x; uo[1] = a.y; uo[2] = a.z; uo[3] = a.w;
        uo[4] = b.x; uo[5] = b.y; uo[6] = b.z; uo[7] = b.w;
    }
    // factor dots (partial over this lane's 8 channels, then seg-reduce)
    float d[N_FACTORS];
    #pragma unroll
    for (int f = 0; f < N_FACTORS; ++f) {
        float p = 0.0f;
        #pragma unroll
        for (int k = 0; k < 8; ++k) p += uo[k] * latent[f * CDIM + seg * 8 + k];
        p += __shfl_xor(p, 1, 64);
        p += __shfl_xor(p, 2, 64);
        p += __shfl_xor(p, 4, 64);
        d[f] = p;
    }
    float m = fmaxf(fmaxf(d[0], d[1]), fmaxf(d[2], d[3]));
    float e0 = expf(d[0] - m), e1 = expf(d[1] - m), e2 = expf(d[2] - m), e3 = expf(d[3] - m);
    float inv_ssum = 1.0f / (e0 + e1 + e2 + e3);

    float ssq = 0.0f;
    #pragma unroll
    for (int k = 0; k < 8; ++k) {
        int c = seg * 8 + k;
        float g = (e0 * dw[0 * CDIM + c] + e1 * dw[1 * CDIM + c] +
                   e2 * dw[2 * CDIM + c] + e3 * dw[3 * CDIM + c]) * inv_ssum;
        acc[k] = acc[k] * (1.0f + g);
        ssq += acc[k] * acc[k];
    }
    ssq += __shfl_xor(ssq, 1, 64);
    ssq += __shfl_xor(ssq, 2, 64);
    ssq += __shfl_xor(ssq, 4, 64);
    float rn = 1.0f / fmaxf(sqrtf(ssq), 1e-12f);
    #pragma unroll
    for (int k = 0; k < 8; ++k) acc[k] *= rn;

    if (lane < 8) {
        size_t base = (size_t)u * CDIM + lane * 8;
        if (!last) {
            *(uint4*)(unew + base) = pack8(acc);
        } else {
            // ures = uemb0 + dequant(uoldb[u]) + o   (uoldb == hop0 output uA)
            float4 a = *(const float4*)(uemb0 + base);
            float4 b = *(const float4*)(uemb0 + base + 4);
            float4 r0, r1;
            r0.x = a.x + uo[0] + acc[0]; r0.y = a.y + uo[1] + acc[1];
            r0.z = a.z + uo[2] + acc[2]; r0.w = a.w + uo[3] + acc[3];
            r1.x = b.x + uo[4] + acc[4]; r1.y = b.y + uo[5] + acc[5];
            r1.z = b.z + uo[6] + acc[6]; r1.w = b.w + uo[7] + acc[7];
            *(float4*)(ures + base) = r0;
            *(float4*)(ures + base + 4) = r1;
        }
    }
}

static inline size_t align16(size_t x) { return (x + 15) & ~(size_t)15; }

extern "C" void kernel_launch(void* const* d_in, const int* in_sizes, int n_in,
                              void* d_out, int out_size, void* d_ws, size_t ws_size,
                              hipStream_t stream) {
    const float* user_emb   = (const float*)d_in[0];
    const float* entity_emb = (const float*)d_in[1];
    const float* latent_emb = (const float*)d_in[2];
    const float* weight     = (const float*)d_in[3];
    const float* att        = (const float*)d_in[4];
    const int*   edge_index = (const int*)d_in[5];
    const int*   edge_type  = (const int*)d_in[6];
    const int*   inter_rows = (const int*)d_in[7];
    const int*   inter_cols = (const int*)d_in[8];
    const float* inter_vals = (const float*)d_in[9];

    float* eres = (float*)d_out;
    float* ures = eres + (size_t)N_ENTITIES * CDIM;
    float* cor  = ures + (size_t)N_USERS * CDIM;

    char* ws = (char*)d_ws;
    u16*   ebf  = (u16*)ws;   ws += align16(sizeof(u16) * (size_t)N_ENTITIES * CDIM);
    u16*   eA   = (u16*)ws;   ws += align16(sizeof(u16) * (size_t)N_ENTITIES * CDIM);
    u16*   uA   = (u16*)ws;   ws += align16(sizeof(u16) * (size_t)N_USERS * CDIM);
    int*   eoff = (int*)ws;   ws += align16(sizeof(int) * (N_ENTITIES + 1));
    int*   ecnt = (int*)ws;   ws += align16(sizeof(int) * N_ENTITIES);
    int*   ecur = (int*)ws;   ws += align16(sizeof(int) * N_ENTITIES);
    int*   epk  = (int*)ws;   ws += align16(sizeof(int) * N_EDGES);
    int*   uoff = (int*)ws;   ws += align16(sizeof(int) * (N_USERS + 1));
    int*   ucnt = (int*)ws;   ws += align16(sizeof(int) * N_USERS);
    int*   ucur = (int*)ws;   ws += align16(sizeof(int) * N_USERS);
    int*   ucol = (int*)ws;   ws += align16(sizeof(int) * NNZ);
    float* uval = (float*)ws; ws += align16(sizeof(float) * NNZ);
    int*   ebsum = (int*)ws;  ws += align16(sizeof(int) * 128);
    int*   ubsum = (int*)ws;  ws += align16(sizeof(int) * 64);
    float* dw   = (float*)ws; ws += align16(sizeof(float) * N_FACTORS * CDIM);

    const int* head = edge_index;
    const int* tail = edge_index + N_EDGES;

    const int NB_E = (N_ENTITIES + SCAN_CHUNK - 1) / SCAN_CHUNK;   // 98
    const int NB_U = (N_USERS + SCAN_CHUNK - 1) / SCAN_CHUNK;      // 49

    // --- CSR build + bf16 conversion ---
    (void)hipMemsetAsync(ecnt, 0, sizeof(int) * N_ENTITIES, stream);
    (void)hipMemsetAsync(ucnt, 0, sizeof(int) * N_USERS, stream);
    cvt_bf16<<<(N_ENTITIES * CDIM / 8 + 255) / 256, 256, 0, stream>>>(
        entity_emb, ebf, N_ENTITIES * CDIM / 8);
    hist_kernel<<<(N_EDGES + 255) / 256, 256, 0, stream>>>(head, N_EDGES, ecnt);
    hist_kernel<<<(NNZ + 255) / 256, 256, 0, stream>>>(inter_rows, NNZ, ucnt);
    scan_p1<<<NB_E, 256, 0, stream>>>(ecnt, N_ENTITIES, ebsum);
    scan_p2<<<1, 64, 0, stream>>>(ebsum, NB_E, eoff + N_ENTITIES);
    scan_p3<<<NB_E, 256, 0, stream>>>(ecnt, N_ENTITIES, ebsum, eoff);
    scan_p1<<<NB_U, 256, 0, stream>>>(ucnt, N_USERS, ubsum);
    scan_p2<<<1, 64, 0, stream>>>(ubsum, NB_U, uoff + N_USERS);
    scan_p3<<<NB_U, 256, 0, stream>>>(ucnt, N_USERS, ubsum, uoff);
    (void)hipMemcpyAsync(ecur, eoff, sizeof(int) * N_ENTITIES, hipMemcpyDeviceToDevice, stream);
    (void)hipMemcpyAsync(ucur, uoff, sizeof(int) * N_USERS, hipMemcpyDeviceToDevice, stream);
    edge_scatter<<<(N_EDGES + 255) / 256, 256, 0, stream>>>(head, tail, edge_type, ecur, epk);
    inter_scatter<<<(NNZ + 255) / 256, 256, 0, stream>>>(inter_rows, inter_cols, inter_vals,
                                                         ucur, ucol, uval);

    disen_kernel<<<1, 256, 0, stream>>>(att, weight, dw);
    cor_kernel<<<1, 64, 0, stream>>>(att, cor);

    const int kg_grid   = (N_ENTITIES * 64) / 256;   // 50000
    const int user_grid = (N_USERS * 64) / 256;      // 25000

    // --- hop 0: gather from ebf, write bf16 eA/uA only ---
    kg_fused8<<<kg_grid, 256, 0, stream>>>(ebf, eoff, epk, weight,
                                           (const float*)nullptr, eA, (float*)nullptr, 0);
    user_fused8<<<user_grid, 256, 0, stream>>>(user_emb, (const u16*)nullptr, ebf,
                                               uoff, ucol, uval, latent_emb, dw,
                                               (const float*)nullptr, uA, (float*)nullptr, 0);
    // --- hop 1: gather from eA, write res = emb0 + o0 + o1 (f32, once) ---
    kg_fused8<<<kg_grid, 256, 0, stream>>>(eA, eoff, epk, weight,
                                           entity_emb, (u16*)nullptr, eres, 1);
    user_fused8<<<user_grid, 256, 0, stream>>>((const float*)nullptr, uA, eA,
                                               uoff, ucol, uval, latent_emb, dw,
                                               user_emb, (u16*)nullptr, ures, 1);
}

// Round 7
// 435.604 us; speedup vs baseline: 2.7062x; 1.4423x over previous
//
#include <hip/hip_runtime.h>
#include <math.h>

#define N_USERS    100000
#define N_ENTITIES 200000
#define N_EDGES    1000000
#define NNZ        1000000
#define CDIM       64
#define N_FACTORS  4
#define N_REL      10
#define TEMP       0.2f
#define SCAN_CHUNK 2048

typedef unsigned int u32;
typedef unsigned short u16;

__device__ __forceinline__ float bflo(u32 w) { return __uint_as_float(w << 16); }
__device__ __forceinline__ float bfhi(u32 w) { return __uint_as_float(w & 0xFFFF0000u); }
__device__ __forceinline__ u16 f2bf(float f) {
    u32 u = __float_as_uint(f);
    u32 r = u + 0x7FFFu + ((u >> 16) & 1u);   // RNE
    return (u16)(r >> 16);
}
__device__ __forceinline__ void unpack8(uint4 rv, float* x) {
    x[0] = bflo(rv.x); x[1] = bfhi(rv.x);
    x[2] = bflo(rv.y); x[3] = bfhi(rv.y);
    x[4] = bflo(rv.z); x[5] = bfhi(rv.z);
    x[6] = bflo(rv.w); x[7] = bfhi(rv.w);
}
__device__ __forceinline__ uint4 pack8(const float* x) {
    uint4 o;
    o.x = (u32)f2bf(x[0]) | ((u32)f2bf(x[1]) << 16);
    o.y = (u32)f2bf(x[2]) | ((u32)f2bf(x[3]) << 16);
    o.z = (u32)f2bf(x[4]) | ((u32)f2bf(x[5]) << 16);
    o.w = (u32)f2bf(x[6]) | ((u32)f2bf(x[7]) << 16);
    return o;
}

// --- f32 -> bf16 table conversion (8 elems/thread) --------------------------
__global__ __launch_bounds__(256) void cvt_bf16(const float* __restrict__ in,
                                                u16* __restrict__ out, int n8) {
    int i = blockIdx.x * 256 + threadIdx.x;
    if (i >= n8) return;
    const float4* p = (const float4*)(in + (size_t)i * 8);
    float4 a = p[0], b = p[1];
    float x[8] = {a.x, a.y, a.z, a.w, b.x, b.y, b.z, b.w};
    *(uint4*)(out + (size_t)i * 8) = pack8(x);
}

// --- histogram --------------------------------------------------------------
__global__ __launch_bounds__(256) void hist_kernel(const int* __restrict__ idx, int n,
                                                   int* __restrict__ cnt) {
    int i = blockIdx.x * 256 + threadIdx.x;
    if (i < n) atomicAdd(&cnt[idx[i]], 1);
}

// --- 3-phase exclusive scan -------------------------------------------------
__global__ __launch_bounds__(256) void scan_p1(const int* __restrict__ cnt, int n,
                                               int* __restrict__ bsum) {
    __shared__ int s[256];
    int b = blockIdx.x, t = threadIdx.x;
    int base = b * SCAN_CHUNK;
    int acc = 0;
    for (int k = t; k < SCAN_CHUNK; k += 256) {
        int i = base + k;
        if (i < n) acc += cnt[i];
    }
    s[t] = acc; __syncthreads();
    for (int d = 128; d > 0; d >>= 1) { if (t < d) s[t] += s[t + d]; __syncthreads(); }
    if (t == 0) bsum[b] = s[0];
}

// parallel block-sum scan, nb <= 128 (NB_E=98, NB_U=49)
__global__ __launch_bounds__(128) void scan_p2(int* bsum, int nb, int* off_n) {
    __shared__ int s[128];
    int t = threadIdx.x;
    int v = (t < nb) ? bsum[t] : 0;
    s[t] = v; __syncthreads();
    #pragma unroll
    for (int d = 1; d < 128; d <<= 1) {
        int x = (t >= d) ? s[t - d] : 0;
        __syncthreads();
        s[t] += x;
        __syncthreads();
    }
    if (t < nb) bsum[t] = s[t] - v;          // exclusive
    if (t == nb - 1) *off_n = s[t];          // total
}

// writes both off[] and cur[] (cursor copy for the scatter pass)
__global__ __launch_bounds__(256) void scan_p3(const int* __restrict__ cnt, int n,
                                               const int* __restrict__ bsum,
                                               int* __restrict__ off,
                                               int* __restrict__ cur) {
    __shared__ int s[256];
    int b = blockIdx.x, t = threadIdx.x;
    int base = b * SCAN_CHUNK + t * 8;
    int v[8]; int acc = 0;
    #pragma unroll
    for (int k = 0; k < 8; ++k) { int i = base + k; v[k] = (i < n) ? cnt[i] : 0; acc += v[k]; }
    s[t] = acc; __syncthreads();
    for (int d = 1; d < 256; d <<= 1) {
        int x = (t >= d) ? s[t - d] : 0;
        __syncthreads();
        s[t] += x;
        __syncthreads();
    }
    int excl = s[t] - acc + bsum[b];
    #pragma unroll
    for (int k = 0; k < 8; ++k) {
        int i = base + k;
        if (i < n) { off[i] = excl; cur[i] = excl; excl += v[k]; }
    }
}

// --- CSR scatter ------------------------------------------------------------
__global__ __launch_bounds__(256) void edge_scatter(const int* __restrict__ head,
                                                    const int* __restrict__ tail,
                                                    const int* __restrict__ etype,
                                                    int* __restrict__ cursor,
                                                    int* __restrict__ epk) {
    int i = blockIdx.x * 256 + threadIdx.x;
    if (i >= N_EDGES) return;
    int h = head[i];
    int pos = atomicAdd(&cursor[h], 1);
    epk[pos] = tail[i] | ((etype[i] - 1) << 20);
}

__global__ __launch_bounds__(256) void inter_scatter(const int* __restrict__ rows,
                                                     const int* __restrict__ cols,
                                                     const float* __restrict__ vals,
                                                     int* __restrict__ cursor,
                                                     int2* __restrict__ ucv) {
    int i = blockIdx.x * 256 + threadIdx.x;
    if (i >= NNZ) return;
    int r = rows[i];
    int pos = atomicAdd(&cursor[r], 1);
    int2 p; p.x = cols[i]; p.y = __float_as_int(vals[i]);
    ucv[pos] = p;
}

// --- disen_weight + cor (fused, single tiny launch) -------------------------
__global__ __launch_bounds__(256) void disen_cor_kernel(const float* __restrict__ att,
                                                        const float* __restrict__ weight,
                                                        float* __restrict__ dw,
                                                        float* __restrict__ cor_out) {
    int tid = threadIdx.x;
    int f = tid >> 6, c = tid & 63;
    float m = -1e30f;
    for (int r = 0; r < N_REL; ++r) m = fmaxf(m, att[f * N_REL + r]);
    float e[N_REL], s = 0.0f;
    for (int r = 0; r < N_REL; ++r) { e[r] = __expf(att[f * N_REL + r] - m); s += e[r]; }
    float acc = 0.0f;
    for (int r = 0; r < N_REL; ++r) acc += (e[r] / s) * weight[r * CDIM + c];
    dw[f * CDIM + c] = acc;

    if (tid == 0) {
        float rowsum[N_FACTORS];
        for (int ff = 0; ff < N_FACTORS; ++ff) {
            float ss = 0.0f;
            for (int j = 0; j < N_REL; ++j) ss += att[ff * N_REL + j];
            rowsum[ff] = ss;
        }
        float cor = 0.0f;
        for (int i = 0; i < N_REL; ++i) {
            float nsq = 0.0f, ttl = 0.0f;
            for (int ff = 0; ff < N_FACTORS; ++ff) {
                float a = att[ff * N_REL + i];
                nsq += a * a;
                ttl += a * rowsum[ff];
            }
            float n = sqrtf(nsq);
            float pos = 0.0f;
            for (int ff = 0; ff < N_FACTORS; ++ff) {
                float a = att[ff * N_REL + i] / n;
                pos += a * a;
            }
            cor += (ttl - pos) / TEMP;
        }
        *cor_out = cor;
    }
}

// --- fused KG hop, 8 entities per wave --------------------------------------
// slot = lane>>3 owns an entity; seg = lane&7 owns 8 channels. Serial edge walk
// per slot; accumulators stay in-lane (no cross-slot reduce).
__global__ __launch_bounds__(256) void kg_fusedMU(const u16* __restrict__ esrc,
                                                  const int* __restrict__ eoff,
                                                  const int* __restrict__ epk,
                                                  const float* __restrict__ weight,
                                                  const float* __restrict__ emb0,
                                                  u16* __restrict__ enew,
                                                  float* __restrict__ eres,
                                                  int last) {
    int wid = (blockIdx.x * 256 + threadIdx.x) >> 6;
    int lane = threadIdx.x & 63;
    int slot = lane >> 3, seg = lane & 7;
    int h = wid * 8 + slot;                     // 200000 = 25000 waves * 8, exact
    int s = eoff[h], e = eoff[h + 1];
    int d = e - s;
    int dmax = d;
    dmax = max(dmax, __shfl_xor(dmax, 8, 64));
    dmax = max(dmax, __shfl_xor(dmax, 16, 64));
    dmax = max(dmax, __shfl_xor(dmax, 32, 64));

    float acc[8];
    #pragma unroll
    for (int k = 0; k < 8; ++k) acc[k] = 0.0f;

    for (int it = 0; it < dmax; ++it) {
        if (it < d) {
            int p = epk[s + it];
            int t = p & 0xFFFFF, r = p >> 20;
            uint4 rv = *(const uint4*)(esrc + (size_t)t * CDIM + seg * 8);
            float x[8]; unpack8(rv, x);
            const float4* wp = (const float4*)(weight + r * CDIM + seg * 8);
            float4 w0 = wp[0], w1 = wp[1];
            acc[0] += x[0] * w0.x; acc[1] += x[1] * w0.y;
            acc[2] += x[2] * w0.z; acc[3] += x[3] * w0.w;
            acc[4] += x[4] * w1.x; acc[5] += x[5] * w1.y;
            acc[6] += x[6] * w1.z; acc[7] += x[7] * w1.w;
        }
    }
    float inv = 1.0f / fmaxf((float)d, 1.0f);
    float ssq = 0.0f;
    #pragma unroll
    for (int k = 0; k < 8; ++k) { acc[k] *= inv; ssq += acc[k] * acc[k]; }
    ssq += __shfl_xor(ssq, 1, 64);
    ssq += __shfl_xor(ssq, 2, 64);
    ssq += __shfl_xor(ssq, 4, 64);
    float rn = 1.0f / fmaxf(sqrtf(ssq), 1e-12f);
    #pragma unroll
    for (int k = 0; k < 8; ++k) acc[k] *= rn;

    size_t base = (size_t)h * CDIM + seg * 8;
    if (!last) {
        *(uint4*)(enew + base) = pack8(acc);
    } else {
        uint4 pv = *(const uint4*)(esrc + base);   // esrc == hop0 output eA
        float o0[8]; unpack8(pv, o0);
        float4 a = *(const float4*)(emb0 + base);
        float4 b = *(const float4*)(emb0 + base + 4);
        float4 r0, r1;
        r0.x = a.x + o0[0] + acc[0]; r0.y = a.y + o0[1] + acc[1];
        r0.z = a.z + o0[2] + acc[2]; r0.w = a.w + o0[3] + acc[3];
        r1.x = b.x + o0[4] + acc[4]; r1.y = b.y + o0[5] + acc[5];
        r1.z = b.z + o0[6] + acc[6]; r1.w = b.w + o0[7] + acc[7];
        *(float4*)(eres + base) = r0;
        *(float4*)(eres + base + 4) = r1;
    }
}

// --- fused user hop, 8 users per wave ---------------------------------------
__global__ __launch_bounds__(256) void user_fusedMU(const float* __restrict__ uoldf,
                                                    const u16* __restrict__ uoldb,
                                                    const u16* __restrict__ esrc,
                                                    const int* __restrict__ uoff,
                                                    const int2* __restrict__ ucv,
                                                    const float* __restrict__ latent,
                                                    const float* __restrict__ dw,
                                                    const float* __restrict__ uemb0,
                                                    u16* __restrict__ unew,
                                                    float* __restrict__ ures,
                                                    int last) {
    int wid = (blockIdx.x * 256 + threadIdx.x) >> 6;
    int lane = threadIdx.x & 63;
    int slot = lane >> 3, seg = lane & 7;
    int u = wid * 8 + slot;                     // 100000 = 12500 waves * 8, exact
    int s = uoff[u], e = uoff[u + 1];
    int d = e - s;
    int dmax = d;
    dmax = max(dmax, __shfl_xor(dmax, 8, 64));
    dmax = max(dmax, __shfl_xor(dmax, 16, 64));
    dmax = max(dmax, __shfl_xor(dmax, 32, 64));

    float acc[8];
    #pragma unroll
    for (int k = 0; k < 8; ++k) acc[k] = 0.0f;

    for (int it = 0; it < dmax; ++it) {
        if (it < d) {
            int2 p = ucv[s + it];
            float v = __int_as_float(p.y);
            uint4 rv = *(const uint4*)(esrc + (size_t)p.x * CDIM + seg * 8);
            float x[8]; unpack8(rv, x);
            #pragma unroll
            for (int k = 0; k < 8; ++k) acc[k] += v * x[k];
        }
    }

    // current user row, channels seg*8..+8
    float uo[8];
    size_t ubase = (size_t)u * CDIM + seg * 8;
    if (uoldb) {
        uint4 pv = *(const uint4*)(uoldb + ubase);
        unpack8(pv, uo);
    } else {
        float4 a = *(const float4*)(uoldf + ubase);
        float4 b = *(const float4*)(uoldf + ubase + 4);
        uo[0] = a.x; uo[1] = a.y; uo[2] = a.z; uo[3] = a.w;
        uo[4] = b.x; uo[5] = b.y; uo[6] = b.z; uo[7] = b.w;
    }
    // factor dots: partial over this lane's 8 channels, reduce over slot (xor 1,2,4)
    float dts[N_FACTORS];
    #pragma unroll
    for (int f = 0; f < N_FACTORS; ++f) {
        const float4* lp = (const float4*)(latent + f * CDIM + seg * 8);
        float4 l0 = lp[0], l1 = lp[1];
        float p = uo[0] * l0.x + uo[1] * l0.y + uo[2] * l0.z + uo[3] * l0.w +
                  uo[4] * l1.x + uo[5] * l1.y + uo[6] * l1.z + uo[7] * l1.w;
        p += __shfl_xor(p, 1, 64);
        p += __shfl_xor(p, 2, 64);
        p += __shfl_xor(p, 4, 64);
        dts[f] = p;
    }
    float m = fmaxf(fmaxf(dts[0], dts[1]), fmaxf(dts[2], dts[3]));
    float e0 = __expf(dts[0] - m), e1 = __expf(dts[1] - m);
    float e2 = __expf(dts[2] - m), e3 = __expf(dts[3] - m);
    float inv_ssum = 1.0f / (e0 + e1 + e2 + e3);
    e0 *= inv_ssum; e1 *= inv_ssum; e2 *= inv_ssum; e3 *= inv_ssum;

    const float4* d0p = (const float4*)(dw + 0 * CDIM + seg * 8);
    const float4* d1p = (const float4*)(dw + 1 * CDIM + seg * 8);
    const float4* d2p = (const float4*)(dw + 2 * CDIM + seg * 8);
    const float4* d3p = (const float4*)(dw + 3 * CDIM + seg * 8);
    float4 ga0 = d0p[0], ga1 = d0p[1];
    float4 gb0 = d1p[0], gb1 = d1p[1];
    float4 gc0 = d2p[0], gc1 = d2p[1];
    float4 gd0 = d3p[0], gd1 = d3p[1];
    float g[8];
    g[0] = e0 * ga0.x + e1 * gb0.x + e2 * gc0.x + e3 * gd0.x;
    g[1] = e0 * ga0.y + e1 * gb0.y + e2 * gc0.y + e3 * gd0.y;
    g[2] = e0 * ga0.z + e1 * gb0.z + e2 * gc0.z + e3 * gd0.z;
    g[3] = e0 * ga0.w + e1 * gb0.w + e2 * gc0.w + e3 * gd0.w;
    g[4] = e0 * ga1.x + e1 * gb1.x + e2 * gc1.x + e3 * gd1.x;
    g[5] = e0 * ga1.y + e1 * gb1.y + e2 * gc1.y + e3 * gd1.y;
    g[6] = e0 * ga1.z + e1 * gb1.z + e2 * gc1.z + e3 * gd1.z;
    g[7] = e0 * ga1.w + e1 * gb1.w + e2 * gc1.w + e3 * gd1.w;

    float ssq = 0.0f;
    #pragma unroll
    for (int k = 0; k < 8; ++k) {
        acc[k] = acc[k] * (1.0f + g[k]);
        ssq += acc[k] * acc[k];
    }
    ssq += __shfl_xor(ssq, 1, 64);
    ssq += __shfl_xor(ssq, 2, 64);
    ssq += __shfl_xor(ssq, 4, 64);
    float rn = 1.0f / fmaxf(sqrtf(ssq), 1e-12f);
    #pragma unroll
    for (int k = 0; k < 8; ++k) acc[k] *= rn;

    if (!last) {
        *(uint4*)(unew + ubase) = pack8(acc);
    } else {
        // ures = uemb0 + uo + acc   (uo == hop0 output, dequantized above)
        float4 a = *(const float4*)(uemb0 + ubase);
        float4 b = *(const float4*)(uemb0 + ubase + 4);
        float4 r0, r1;
        r0.x = a.x + uo[0] + acc[0]; r0.y = a.y + uo[1] + acc[1];
        r0.z = a.z + uo[2] + acc[2]; r0.w = a.w + uo[3] + acc[3];
        r1.x = b.x + uo[4] + acc[4]; r1.y = b.y + uo[5] + acc[5];
        r1.z = b.z + uo[6] + acc[6]; r1.w = b.w + uo[7] + acc[7];
        *(float4*)(ures + ubase) = r0;
        *(float4*)(ures + ubase + 4) = r1;
    }
}

static inline size_t align16(size_t x) { return (x + 15) & ~(size_t)15; }

extern "C" void kernel_launch(void* const* d_in, const int* in_sizes, int n_in,
                              void* d_out, int out_size, void* d_ws, size_t ws_size,
                              hipStream_t stream) {
    const float* user_emb   = (const float*)d_in[0];
    const float* entity_emb = (const float*)d_in[1];
    const float* latent_emb = (const float*)d_in[2];
    const float* weight     = (const float*)d_in[3];
    const float* att        = (const float*)d_in[4];
    const int*   edge_index = (const int*)d_in[5];
    const int*   edge_type  = (const int*)d_in[6];
    const int*   inter_rows = (const int*)d_in[7];
    const int*   inter_cols = (const int*)d_in[8];
    const float* inter_vals = (const float*)d_in[9];

    float* eres = (float*)d_out;
    float* ures = eres + (size_t)N_ENTITIES * CDIM;
    float* cor  = ures + (size_t)N_USERS * CDIM;

    char* ws = (char*)d_ws;
    u16*   ebf  = (u16*)ws;   ws += align16(sizeof(u16) * (size_t)N_ENTITIES * CDIM);
    u16*   eA   = (u16*)ws;   ws += align16(sizeof(u16) * (size_t)N_ENTITIES * CDIM);
    u16*   uA   = (u16*)ws;   ws += align16(sizeof(u16) * (size_t)N_USERS * CDIM);
    int*   eoff = (int*)ws;   ws += align16(sizeof(int) * (N_ENTITIES + 1));
    int*   ecnt = (int*)ws;   ws += align16(sizeof(int) * N_ENTITIES);
    int*   ecur = (int*)ws;   ws += align16(sizeof(int) * N_ENTITIES);
    int*   epk  = (int*)ws;   ws += align16(sizeof(int) * N_EDGES);
    int*   uoff = (int*)ws;   ws += align16(sizeof(int) * (N_USERS + 1));
    int*   ucnt = (int*)ws;   ws += align16(sizeof(int) * N_USERS);
    int*   ucur = (int*)ws;   ws += align16(sizeof(int) * N_USERS);
    int2*  ucv  = (int2*)ws;  ws += align16(sizeof(int2) * NNZ);
    int*   ebsum = (int*)ws;  ws += align16(sizeof(int) * 128);
    int*   ubsum = (int*)ws;  ws += align16(sizeof(int) * 128);
    float* dw   = (float*)ws; ws += align16(sizeof(float) * N_FACTORS * CDIM);

    const int* head = edge_index;
    const int* tail = edge_index + N_EDGES;

    const int NB_E = (N_ENTITIES + SCAN_CHUNK - 1) / SCAN_CHUNK;   // 98  (<=128)
    const int NB_U = (N_USERS + SCAN_CHUNK - 1) / SCAN_CHUNK;      // 49  (<=128)

    // --- CSR build + bf16 conversion ---
    (void)hipMemsetAsync(ecnt, 0, sizeof(int) * N_ENTITIES, stream);
    (void)hipMemsetAsync(ucnt, 0, sizeof(int) * N_USERS, stream);
    cvt_bf16<<<(N_ENTITIES * CDIM / 8 + 255) / 256, 256, 0, stream>>>(
        entity_emb, ebf, N_ENTITIES * CDIM / 8);
    hist_kernel<<<(N_EDGES + 255) / 256, 256, 0, stream>>>(head, N_EDGES, ecnt);
    hist_kernel<<<(NNZ + 255) / 256, 256, 0, stream>>>(inter_rows, NNZ, ucnt);
    scan_p1<<<NB_E, 256, 0, stream>>>(ecnt, N_ENTITIES, ebsum);
    scan_p2<<<1, 128, 0, stream>>>(ebsum, NB_E, eoff + N_ENTITIES);
    scan_p3<<<NB_E, 256, 0, stream>>>(ecnt, N_ENTITIES, ebsum, eoff, ecur);
    scan_p1<<<NB_U, 256, 0, stream>>>(ucnt, N_USERS, ubsum);
    scan_p2<<<1, 128, 0, stream>>>(ubsum, NB_U, uoff + N_USERS);
    scan_p3<<<NB_U, 256, 0, stream>>>(ucnt, N_USERS, ubsum, uoff, ucur);
    edge_scatter<<<(N_EDGES + 255) / 256, 256, 0, stream>>>(head, tail, edge_type, ecur, epk);
    inter_scatter<<<(NNZ + 255) / 256, 256, 0, stream>>>(inter_rows, inter_cols, inter_vals,
                                                         ucur, ucv);

    disen_cor_kernel<<<1, 256, 0, stream>>>(att, weight, dw, cor);

    const int kg_grid   = N_ENTITIES / 32;   // 6250 blocks * 4 waves * 8 ent
    const int user_grid = N_USERS / 32;      // 3125 blocks * 4 waves * 8 users

    // --- hop 0: gather from ebf, write bf16 eA/uA only ---
    kg_fusedMU<<<kg_grid, 256, 0, stream>>>(ebf, eoff, epk, weight,
                                            (const float*)nullptr, eA, (float*)nullptr, 0);
    user_fusedMU<<<user_grid, 256, 0, stream>>>(user_emb, (const u16*)nullptr, ebf,
                                                uoff, ucv, latent_emb, dw,
                                                (const float*)nullptr, uA, (float*)nullptr, 0);
    // --- hop 1: gather from eA/uA, write res = emb0 + o0 + o1 (f32, once) ---
    kg_fusedMU<<<kg_grid, 256, 0, stream>>>(eA, eoff, epk, weight,
                                            entity_emb, (u16*)nullptr, eres, 1);
    user_fusedMU<<<user_grid, 256, 0, stream>>>((const float*)nullptr, uA, eA,
                                                uoff, ucv, latent_emb, dw,
                                                user_emb, (u16*)nullptr, ures, 1);
}

// Round 8
// 341.560 us; speedup vs baseline: 3.4514x; 1.2753x over previous
//
#include <hip/hip_runtime.h>
#include <math.h>

#define N_USERS    100000
#define N_ENTITIES 200000
#define N_EDGES    1000000
#define NNZ        1000000
#define CDIM       64
#define N_FACTORS  4
#define N_REL      10
#define TEMP       0.2f

#define CB         1024                          // heads per coarse bucket
#define NBE        ((N_ENTITIES + CB - 1) / CB)  // 196
#define NBU        ((N_USERS + CB - 1) / CB)     // 98
#define ACHUNK     4096                          // edges per bin-pass block
#define GA         ((N_EDGES + ACHUNK - 1) / ACHUNK)   // 245

typedef unsigned int u32;
typedef unsigned short u16;

__device__ __forceinline__ float bflo(u32 w) { return __uint_as_float(w << 16); }
__device__ __forceinline__ float bfhi(u32 w) { return __uint_as_float(w & 0xFFFF0000u); }
__device__ __forceinline__ u16 f2bf(float f) {
    u32 u = __float_as_uint(f);
    u32 r = u + 0x7FFFu + ((u >> 16) & 1u);   // RNE
    return (u16)(r >> 16);
}
__device__ __forceinline__ void unpack8(uint4 rv, float* x) {
    x[0] = bflo(rv.x); x[1] = bfhi(rv.x);
    x[2] = bflo(rv.y); x[3] = bfhi(rv.y);
    x[4] = bflo(rv.z); x[5] = bfhi(rv.z);
    x[6] = bflo(rv.w); x[7] = bfhi(rv.w);
}
__device__ __forceinline__ uint4 pack8(const float* x) {
    uint4 o;
    o.x = (u32)f2bf(x[0]) | ((u32)f2bf(x[1]) << 16);
    o.y = (u32)f2bf(x[2]) | ((u32)f2bf(x[3]) << 16);
    o.z = (u32)f2bf(x[4]) | ((u32)f2bf(x[5]) << 16);
    o.w = (u32)f2bf(x[6]) | ((u32)f2bf(x[7]) << 16);
    return o;
}

// --- f32 -> bf16 table conversion (8 elems/thread) --------------------------
__global__ __launch_bounds__(256) void cvt_bf16(const float* __restrict__ in,
                                                u16* __restrict__ out, int n8) {
    int i = blockIdx.x * 256 + threadIdx.x;
    if (i >= n8) return;
    const float4* p = (const float4*)(in + (size_t)i * 8);
    float4 a = p[0], b = p[1];
    float x[8] = {a.x, a.y, a.z, a.w, b.x, b.y, b.z, b.w};
    *(uint4*)(out + (size_t)i * 8) = pack8(x);
}

// --- coarse bucket histogram (bucket = idx>>10, LDS-aggregated) -------------
__global__ __launch_bounds__(256) void coarse_hist(const int* __restrict__ idx, int n,
                                                   int* __restrict__ bhist) {
    __shared__ int lh[256];
    int t = threadIdx.x;
    lh[t] = 0; __syncthreads();
    int base = blockIdx.x * ACHUNK;
    #pragma unroll
    for (int k = 0; k < 16; ++k) {
        int i = base + k * 256 + t;
        if (i < n) atomicAdd(&lh[idx[i] >> 10], 1);
    }
    __syncthreads();
    if (lh[t]) atomicAdd(&bhist[t], lh[t]);
}

// --- single-block exclusive scan of bucket hist (nb <= 256) -----------------
// writes bbase[0..nb], gcur copy, and off_n (= total) for eoff[N]
__global__ __launch_bounds__(256) void bucket_scan(const int* __restrict__ bhist, int nb,
                                                   int* __restrict__ bbase,
                                                   int* __restrict__ gcur,
                                                   int* __restrict__ off_n) {
    __shared__ int s[256];
    int t = threadIdx.x;
    int v = (t < nb) ? bhist[t] : 0;
    s[t] = v; __syncthreads();
    #pragma unroll
    for (int d = 1; d < 256; d <<= 1) {
        int x = (t >= d) ? s[t - d] : 0;
        __syncthreads();
        s[t] += x;
        __syncthreads();
    }
    int excl = s[t] - v;
    if (t < nb) { bbase[t] = excl; gcur[t] = excl; }
    if (t == nb - 1) { bbase[nb] = s[t]; *off_n = s[t]; }
}

// --- bin pass (entity): record = hl<<22 | rel<<18 | tail  (exactly 32 bits) -
__global__ __launch_bounds__(256) void bin_edges(const int* __restrict__ head,
                                                 const int* __restrict__ tail,
                                                 const int* __restrict__ etype,
                                                 int* __restrict__ gcur,
                                                 int* __restrict__ binbuf) {
    __shared__ int lh[256], lbase[256];
    int t = threadIdx.x;
    lh[t] = 0; __syncthreads();
    int base = blockIdx.x * ACHUNK;
    int rec[16], rnk[16], bkt[16];
    #pragma unroll
    for (int k = 0; k < 16; ++k) {
        int i = base + k * 256 + t;
        rnk[k] = -1; rec[k] = 0; bkt[k] = 0;
        if (i < N_EDGES) {
            int h = head[i];
            bkt[k] = h >> 10;
            rec[k] = ((h & 1023) << 22) | ((etype[i] - 1) << 18) | tail[i];
            rnk[k] = atomicAdd(&lh[bkt[k]], 1);
        }
    }
    __syncthreads();
    lbase[t] = lh[t] ? atomicAdd(&gcur[t], lh[t]) : 0;
    __syncthreads();
    #pragma unroll
    for (int k = 0; k < 16; ++k)
        if (rnk[k] >= 0) binbuf[lbase[bkt[k]] + rnk[k]] = rec[k];
}

// --- bin pass (user): record.x = rl<<18 | col, record.y = val bits ----------
__global__ __launch_bounds__(256) void bin_inter(const int* __restrict__ rows,
                                                 const int* __restrict__ cols,
                                                 const float* __restrict__ vals,
                                                 int* __restrict__ gcur,
                                                 int2* __restrict__ binbuf) {
    __shared__ int lh[256], lbase[256];
    int t = threadIdx.x;
    lh[t] = 0; __syncthreads();
    int base = blockIdx.x * ACHUNK;
    int recx[16], recy[16], rnk[16], bkt[16];
    #pragma unroll
    for (int k = 0; k < 16; ++k) {
        int i = base + k * 256 + t;
        rnk[k] = -1; recx[k] = 0; recy[k] = 0; bkt[k] = 0;
        if (i < NNZ) {
            int r = rows[i];
            bkt[k] = r >> 10;
            recx[k] = ((r & 1023) << 18) | cols[i];
            recy[k] = __float_as_int(vals[i]);
            rnk[k] = atomicAdd(&lh[bkt[k]], 1);
        }
    }
    __syncthreads();
    lbase[t] = lh[t] ? atomicAdd(&gcur[t], lh[t]) : 0;
    __syncthreads();
    #pragma unroll
    for (int k = 0; k < 16; ++k)
        if (rnk[k] >= 0) {
            int2 p; p.x = recx[k]; p.y = recy[k];
            binbuf[lbase[bkt[k]] + rnk[k]] = p;
        }
}

// --- per-bucket CSR finalize (entity): eoff + epk ---------------------------
__global__ __launch_bounds__(256) void build_csr_e(const int* __restrict__ bbase,
                                                   const int* __restrict__ binbuf,
                                                   int* __restrict__ eoff,
                                                   int* __restrict__ epk) {
    __shared__ int lh[CB];
    __shared__ int ss[256];
    int b = blockIdx.x, t = threadIdx.x;
    int bstart = bbase[b], bend = bbase[b + 1];
    #pragma unroll
    for (int k = 0; k < 4; ++k) lh[t * 4 + k] = 0;
    __syncthreads();
    for (int j = bstart + t; j < bend; j += 256)
        atomicAdd(&lh[(u32)binbuf[j] >> 22], 1);
    __syncthreads();
    int v[4], acc = 0;
    #pragma unroll
    for (int k = 0; k < 4; ++k) { v[k] = lh[t * 4 + k]; acc += v[k]; }
    ss[t] = acc; __syncthreads();
    #pragma unroll
    for (int d = 1; d < 256; d <<= 1) {
        int x = (t >= d) ? ss[t - d] : 0;
        __syncthreads();
        ss[t] += x;
        __syncthreads();
    }
    int excl = ss[t] - acc;
    int hbase = b * CB;
    #pragma unroll
    for (int k = 0; k < 4; ++k) {
        int hl = t * 4 + k;
        int h = hbase + hl;
        if (h < N_ENTITIES) eoff[h] = bstart + excl;
        lh[hl] = excl;              // becomes the placement cursor
        excl += v[k];
    }
    __syncthreads();
    for (int j = bstart + t; j < bend; j += 256) {
        int rec = binbuf[j];
        int pos = atomicAdd(&lh[(u32)rec >> 22], 1);
        epk[bstart + pos] = rec & 0x3FFFFF;   // rel<<18 | tail
    }
}

// --- per-bucket CSR finalize (user): uoff + ucv -----------------------------
__global__ __launch_bounds__(256) void build_csr_u(const int* __restrict__ bbase,
                                                   const int2* __restrict__ binbuf,
                                                   int* __restrict__ uoff,
                                                   int2* __restrict__ ucv) {
    __shared__ int lh[CB];
    __shared__ int ss[256];
    int b = blockIdx.x, t = threadIdx.x;
    int bstart = bbase[b], bend = bbase[b + 1];
    #pragma unroll
    for (int k = 0; k < 4; ++k) lh[t * 4 + k] = 0;
    __syncthreads();
    for (int j = bstart + t; j < bend; j += 256)
        atomicAdd(&lh[(u32)binbuf[j].x >> 18], 1);
    __syncthreads();
    int v[4], acc = 0;
    #pragma unroll
    for (int k = 0; k < 4; ++k) { v[k] = lh[t * 4 + k]; acc += v[k]; }
    ss[t] = acc; __syncthreads();
    #pragma unroll
    for (int d = 1; d < 256; d <<= 1) {
        int x = (t >= d) ? ss[t - d] : 0;
        __syncthreads();
        ss[t] += x;
        __syncthreads();
    }
    int excl = ss[t] - acc;
    int ubase = b * CB;
    #pragma unroll
    for (int k = 0; k < 4; ++k) {
        int ul = t * 4 + k;
        int u = ubase + ul;
        if (u < N_USERS) uoff[u] = bstart + excl;
        lh[ul] = excl;
        excl += v[k];
    }
    __syncthreads();
    for (int j = bstart + t; j < bend; j += 256) {
        int2 rec = binbuf[j];
        int pos = atomicAdd(&lh[(u32)rec.x >> 18], 1);
        int2 out; out.x = rec.x & 0x3FFFF; out.y = rec.y;
        ucv[bstart + pos] = out;
    }
}

// --- disen_weight + cor (fused, single tiny launch) -------------------------
__global__ __launch_bounds__(256) void disen_cor_kernel(const float* __restrict__ att,
                                                        const float* __restrict__ weight,
                                                        float* __restrict__ dw,
                                                        float* __restrict__ cor_out) {
    int tid = threadIdx.x;
    int f = tid >> 6, c = tid & 63;
    float m = -1e30f;
    for (int r = 0; r < N_REL; ++r) m = fmaxf(m, att[f * N_REL + r]);
    float e[N_REL], s = 0.0f;
    for (int r = 0; r < N_REL; ++r) { e[r] = __expf(att[f * N_REL + r] - m); s += e[r]; }
    float acc = 0.0f;
    for (int r = 0; r < N_REL; ++r) acc += (e[r] / s) * weight[r * CDIM + c];
    dw[f * CDIM + c] = acc;

    if (tid == 0) {
        float rowsum[N_FACTORS];
        for (int ff = 0; ff < N_FACTORS; ++ff) {
            float ss = 0.0f;
            for (int j = 0; j < N_REL; ++j) ss += att[ff * N_REL + j];
            rowsum[ff] = ss;
        }
        float cor = 0.0f;
        for (int i = 0; i < N_REL; ++i) {
            float nsq = 0.0f, ttl = 0.0f;
            for (int ff = 0; ff < N_FACTORS; ++ff) {
                float a = att[ff * N_REL + i];
                nsq += a * a;
                ttl += a * rowsum[ff];
            }
            float n = sqrtf(nsq);
            float pos = 0.0f;
            for (int ff = 0; ff < N_FACTORS; ++ff) {
                float a = att[ff * N_REL + i] / n;
                pos += a * a;
            }
            cor += (ttl - pos) / TEMP;
        }
        *cor_out = cor;
    }
}

// --- fused KG hop, 8 entities per wave, 2-deep pipelined gather -------------
__global__ __launch_bounds__(256) void kg_fusedMU(const u16* __restrict__ esrc,
                                                  const int* __restrict__ eoff,
                                                  const int* __restrict__ epk,
                                                  const float* __restrict__ weight,
                                                  const float* __restrict__ emb0,
                                                  u16* __restrict__ enew,
                                                  float* __restrict__ eres,
                                                  int last) {
    int wid = (blockIdx.x * 256 + threadIdx.x) >> 6;
    int lane = threadIdx.x & 63;
    int slot = lane >> 3, seg = lane & 7;
    int h = wid * 8 + slot;
    int s = eoff[h], e = eoff[h + 1];
    int d = e - s;
    int dmax = d;
    dmax = max(dmax, __shfl_xor(dmax, 8, 64));
    dmax = max(dmax, __shfl_xor(dmax, 16, 64));
    dmax = max(dmax, __shfl_xor(dmax, 32, 64));

    float acc[8];
    #pragma unroll
    for (int k = 0; k < 8; ++k) acc[k] = 0.0f;
    const uint4 uz = make_uint4(0u, 0u, 0u, 0u);

    for (int it = 0; it < dmax; it += 2) {
        bool q0 = it < d, q1 = (it + 1) < d;
        int p0 = q0 ? epk[s + it] : 0;
        int p1 = q1 ? epk[s + it + 1] : 0;
        uint4 rv0 = q0 ? *(const uint4*)(esrc + (size_t)(p0 & 0x3FFFF) * CDIM + seg * 8) : uz;
        uint4 rv1 = q1 ? *(const uint4*)(esrc + (size_t)(p1 & 0x3FFFF) * CDIM + seg * 8) : uz;
        {
            float x[8]; unpack8(rv0, x);
            const float4* wp = (const float4*)(weight + (p0 >> 18) * CDIM + seg * 8);
            float4 w0 = wp[0], w1 = wp[1];
            acc[0] += x[0] * w0.x; acc[1] += x[1] * w0.y;
            acc[2] += x[2] * w0.z; acc[3] += x[3] * w0.w;
            acc[4] += x[4] * w1.x; acc[5] += x[5] * w1.y;
            acc[6] += x[6] * w1.z; acc[7] += x[7] * w1.w;
        }
        {
            float x[8]; unpack8(rv1, x);
            const float4* wp = (const float4*)(weight + (p1 >> 18) * CDIM + seg * 8);
            float4 w0 = wp[0], w1 = wp[1];
            acc[0] += x[0] * w0.x; acc[1] += x[1] * w0.y;
            acc[2] += x[2] * w0.z; acc[3] += x[3] * w0.w;
            acc[4] += x[4] * w1.x; acc[5] += x[5] * w1.y;
            acc[6] += x[6] * w1.z; acc[7] += x[7] * w1.w;
        }
    }
    float inv = 1.0f / fmaxf((float)d, 1.0f);
    float ssq = 0.0f;
    #pragma unroll
    for (int k = 0; k < 8; ++k) { acc[k] *= inv; ssq += acc[k] * acc[k]; }
    ssq += __shfl_xor(ssq, 1, 64);
    ssq += __shfl_xor(ssq, 2, 64);
    ssq += __shfl_xor(ssq, 4, 64);
    float rn = 1.0f / fmaxf(sqrtf(ssq), 1e-12f);
    #pragma unroll
    for (int k = 0; k < 8; ++k) acc[k] *= rn;

    size_t base = (size_t)h * CDIM + seg * 8;
    if (!last) {
        *(uint4*)(enew + base) = pack8(acc);
    } else {
        uint4 pv = *(const uint4*)(esrc + base);   // esrc == hop0 output eA
        float o0[8]; unpack8(pv, o0);
        float4 a = *(const float4*)(emb0 + base);
        float4 b = *(const float4*)(emb0 + base + 4);
        float4 r0, r1;
        r0.x = a.x + o0[0] + acc[0]; r0.y = a.y + o0[1] + acc[1];
        r0.z = a.z + o0[2] + acc[2]; r0.w = a.w + o0[3] + acc[3];
        r1.x = b.x + o0[4] + acc[4]; r1.y = b.y + o0[5] + acc[5];
        r1.z = b.z + o0[6] + acc[6]; r1.w = b.w + o0[7] + acc[7];
        *(float4*)(eres + base) = r0;
        *(float4*)(eres + base + 4) = r1;
    }
}

// --- fused user hop, 8 users per wave, 2-deep pipelined gather --------------
__global__ __launch_bounds__(256) void user_fusedMU(const float* __restrict__ uoldf,
                                                    const u16* __restrict__ uoldb,
                                                    const u16* __restrict__ esrc,
                                                    const int* __restrict__ uoff,
                                                    const int2* __restrict__ ucv,
                                                    const float* __restrict__ latent,
                                                    const float* __restrict__ dw,
                                                    const float* __restrict__ uemb0,
                                                    u16* __restrict__ unew,
                                                    float* __restrict__ ures,
                                                    int last) {
    int wid = (blockIdx.x * 256 + threadIdx.x) >> 6;
    int lane = threadIdx.x & 63;
    int slot = lane >> 3, seg = lane & 7;
    int u = wid * 8 + slot;
    int s = uoff[u], e = uoff[u + 1];
    int d = e - s;
    int dmax = d;
    dmax = max(dmax, __shfl_xor(dmax, 8, 64));
    dmax = max(dmax, __shfl_xor(dmax, 16, 64));
    dmax = max(dmax, __shfl_xor(dmax, 32, 64));

    float acc[8];
    #pragma unroll
    for (int k = 0; k < 8; ++k) acc[k] = 0.0f;
    const uint4 uz = make_uint4(0u, 0u, 0u, 0u);
    const int2 cz = make_int2(0, 0);

    for (int it = 0; it < dmax; it += 2) {
        bool q0 = it < d, q1 = (it + 1) < d;
        int2 c0 = q0 ? ucv[s + it] : cz;
        int2 c1 = q1 ? ucv[s + it + 1] : cz;
        uint4 rv0 = q0 ? *(const uint4*)(esrc + (size_t)c0.x * CDIM + seg * 8) : uz;
        uint4 rv1 = q1 ? *(const uint4*)(esrc + (size_t)c1.x * CDIM + seg * 8) : uz;
        {
            float v = __int_as_float(c0.y);
            float x[8]; unpack8(rv0, x);
            #pragma unroll
            for (int k = 0; k < 8; ++k) acc[k] += v * x[k];
        }
        {
            float v = __int_as_float(c1.y);
            float x[8]; unpack8(rv1, x);
            #pragma unroll
            for (int k = 0; k < 8; ++k) acc[k] += v * x[k];
        }
    }

    float uo[8];
    size_t ubase = (size_t)u * CDIM + seg * 8;
    if (uoldb) {
        uint4 pv = *(const uint4*)(uoldb + ubase);
        unpack8(pv, uo);
    } else {
        float4 a = *(const float4*)(uoldf + ubase);
        float4 b = *(const float4*)(uoldf + ubase + 4);
        uo[0] = a.x; uo[1] = a.y; uo[2] = a.z; uo[3] = a.w;
        uo[4] = b.x; uo[5] = b.y; uo[6] = b.z; uo[7] = b.w;
    }
    float dts[N_FACTORS];
    #pragma unroll
    for (int f = 0; f < N_FACTORS; ++f) {
        const float4* lp = (const float4*)(latent + f * CDIM + seg * 8);
        float4 l0 = lp[0], l1 = lp[1];
        float p = uo[0] * l0.x + uo[1] * l0.y + uo[2] * l0.z + uo[3] * l0.w +
                  uo[4] * l1.x + uo[5] * l1.y + uo[6] * l1.z + uo[7] * l1.w;
        p += __shfl_xor(p, 1, 64);
        p += __shfl_xor(p, 2, 64);
        p += __shfl_xor(p, 4, 64);
        dts[f] = p;
    }
    float m = fmaxf(fmaxf(dts[0], dts[1]), fmaxf(dts[2], dts[3]));
    float e0 = __expf(dts[0] - m), e1 = __expf(dts[1] - m);
    float e2 = __expf(dts[2] - m), e3 = __expf(dts[3] - m);
    float inv_ssum = 1.0f / (e0 + e1 + e2 + e3);
    e0 *= inv_ssum; e1 *= inv_ssum; e2 *= inv_ssum; e3 *= inv_ssum;

    const float4* d0p = (const float4*)(dw + 0 * CDIM + seg * 8);
    const float4* d1p = (const float4*)(dw + 1 * CDIM + seg * 8);
    const float4* d2p = (const float4*)(dw + 2 * CDIM + seg * 8);
    const float4* d3p = (const float4*)(dw + 3 * CDIM + seg * 8);
    float4 ga0 = d0p[0], ga1 = d0p[1];
    float4 gb0 = d1p[0], gb1 = d1p[1];
    float4 gc0 = d2p[0], gc1 = d2p[1];
    float4 gd0 = d3p[0], gd1 = d3p[1];
    float g[8];
    g[0] = e0 * ga0.x + e1 * gb0.x + e2 * gc0.x + e3 * gd0.x;
    g[1] = e0 * ga0.y + e1 * gb0.y + e2 * gc0.y + e3 * gd0.y;
    g[2] = e0 * ga0.z + e1 * gb0.z + e2 * gc0.z + e3 * gd0.z;
    g[3] = e0 * ga0.w + e1 * gb0.w + e2 * gc0.w + e3 * gd0.w;
    g[4] = e0 * ga1.x + e1 * gb1.x + e2 * gc1.x + e3 * gd1.x;
    g[5] = e0 * ga1.y + e1 * gb1.y + e2 * gc1.y + e3 * gd1.y;
    g[6] = e0 * ga1.z + e1 * gb1.z + e2 * gc1.z + e3 * gd1.z;
    g[7] = e0 * ga1.w + e1 * gb1.w + e2 * gc1.w + e3 * gd1.w;

    float ssq = 0.0f;
    #pragma unroll
    for (int k = 0; k < 8; ++k) {
        acc[k] = acc[k] * (1.0f + g[k]);
        ssq += acc[k] * acc[k];
    }
    ssq += __shfl_xor(ssq, 1, 64);
    ssq += __shfl_xor(ssq, 2, 64);
    ssq += __shfl_xor(ssq, 4, 64);
    float rn = 1.0f / fmaxf(sqrtf(ssq), 1e-12f);
    #pragma unroll
    for (int k = 0; k < 8; ++k) acc[k] *= rn;

    if (!last) {
        *(uint4*)(unew + ubase) = pack8(acc);
    } else {
        float4 a = *(const float4*)(uemb0 + ubase);
        float4 b = *(const float4*)(uemb0 + ubase + 4);
        float4 r0, r1;
        r0.x = a.x + uo[0] + acc[0]; r0.y = a.y + uo[1] + acc[1];
        r0.z = a.z + uo[2] + acc[2]; r0.w = a.w + uo[3] + acc[3];
        r1.x = b.x + uo[4] + acc[4]; r1.y = b.y + uo[5] + acc[5];
        r1.z = b.z + uo[6] + acc[6]; r1.w = b.w + uo[7] + acc[7];
        *(float4*)(ures + ubase) = r0;
        *(float4*)(ures + ubase + 4) = r1;
    }
}

static inline size_t align16(size_t x) { return (x + 15) & ~(size_t)15; }

extern "C" void kernel_launch(void* const* d_in, const int* in_sizes, int n_in,
                              void* d_out, int out_size, void* d_ws, size_t ws_size,
                              hipStream_t stream) {
    const float* user_emb   = (const float*)d_in[0];
    const float* entity_emb = (const float*)d_in[1];
    const float* latent_emb = (const float*)d_in[2];
    const float* weight     = (const float*)d_in[3];
    const float* att        = (const float*)d_in[4];
    const int*   edge_index = (const int*)d_in[5];
    const int*   edge_type  = (const int*)d_in[6];
    const int*   inter_rows = (const int*)d_in[7];
    const int*   inter_cols = (const int*)d_in[8];
    const float* inter_vals = (const float*)d_in[9];

    float* eres = (float*)d_out;
    float* ures = eres + (size_t)N_ENTITIES * CDIM;
    float* cor  = ures + (size_t)N_USERS * CDIM;

    char* ws = (char*)d_ws;
    u16*   ebf   = (u16*)ws;  ws += align16(sizeof(u16) * (size_t)N_ENTITIES * CDIM);
    u16*   eA    = (u16*)ws;  ws += align16(sizeof(u16) * (size_t)N_ENTITIES * CDIM);
    u16*   uA    = (u16*)ws;  ws += align16(sizeof(u16) * (size_t)N_USERS * CDIM);
    int*   eoff  = (int*)ws;  ws += align16(sizeof(int) * (N_ENTITIES + 1));
    int*   epk   = (int*)ws;  ws += align16(sizeof(int) * N_EDGES);
    int*   uoff  = (int*)ws;  ws += align16(sizeof(int) * (N_USERS + 1));
    int2*  ucv   = (int2*)ws; ws += align16(sizeof(int2) * NNZ);
    int*   bine  = (int*)ws;  ws += align16(sizeof(int) * N_EDGES);
    int2*  binu  = (int2*)ws; ws += align16(sizeof(int2) * NNZ);
    int*   bhe   = (int*)ws;  ws += align16(sizeof(int) * 256);
    int*   bhu   = (int*)ws;  ws += align16(sizeof(int) * 256);
    int*   bbe   = (int*)ws;  ws += align16(sizeof(int) * 257);
    int*   bbu   = (int*)ws;  ws += align16(sizeof(int) * 257);
    int*   gce   = (int*)ws;  ws += align16(sizeof(int) * 256);
    int*   gcu   = (int*)ws;  ws += align16(sizeof(int) * 256);
    float* dw    = (float*)ws; ws += align16(sizeof(float) * N_FACTORS * CDIM);

    const int* head = edge_index;
    const int* tail = edge_index + N_EDGES;

    // zero the two coarse histograms (adjacent, 2 KB)
    (void)hipMemsetAsync(bhe, 0, sizeof(int) * 512, stream);

    cvt_bf16<<<(N_ENTITIES * CDIM / 8 + 255) / 256, 256, 0, stream>>>(
        entity_emb, ebf, N_ENTITIES * CDIM / 8);

    // --- CSR build: coarse hist -> bucket scan -> bin -> per-bucket finalize
    coarse_hist<<<GA, 256, 0, stream>>>(head, N_EDGES, bhe);
    coarse_hist<<<GA, 256, 0, stream>>>(inter_rows, NNZ, bhu);
    bucket_scan<<<1, 256, 0, stream>>>(bhe, NBE, bbe, gce, eoff + N_ENTITIES);
    bucket_scan<<<1, 256, 0, stream>>>(bhu, NBU, bbu, gcu, uoff + N_USERS);
    bin_edges<<<GA, 256, 0, stream>>>(head, tail, edge_type, gce, bine);
    bin_inter<<<GA, 256, 0, stream>>>(inter_rows, inter_cols, inter_vals, gcu, binu);
    build_csr_e<<<NBE, 256, 0, stream>>>(bbe, bine, eoff, epk);
    build_csr_u<<<NBU, 256, 0, stream>>>(bbu, binu, uoff, ucv);

    disen_cor_kernel<<<1, 256, 0, stream>>>(att, weight, dw, cor);

    const int kg_grid   = N_ENTITIES / 32;   // 6250 blocks, 8 entities/wave
    const int user_grid = N_USERS / 32;      // 3125 blocks, 8 users/wave

    // --- hop 0: gather from ebf, write bf16 eA/uA only ---
    kg_fusedMU<<<kg_grid, 256, 0, stream>>>(ebf, eoff, epk, weight,
                                            (const float*)nullptr, eA, (float*)nullptr, 0);
    user_fusedMU<<<user_grid, 256, 0, stream>>>(user_emb, (const u16*)nullptr, ebf,
                                                uoff, ucv, latent_emb, dw,
                                                (const float*)nullptr, uA, (float*)nullptr, 0);
    // --- hop 1: gather from eA/uA, write res = emb0 + o0 + o1 (f32, once) ---
    kg_fusedMU<<<kg_grid, 256, 0, stream>>>(eA, eoff, epk, weight,
                                            entity_emb, (u16*)nullptr, eres, 1);
    user_fusedMU<<<user_grid, 256, 0, stream>>>((const float*)nullptr, uA, eA,
                                                uoff, ucv, latent_emb, dw,
                                                user_emb, (u16*)nullptr, ures, 1);
}

// Round 9
// 268.072 us; speedup vs baseline: 4.3975x; 1.2741x over previous
//
#include <hip/hip_runtime.h>
#include <math.h>

#define N_USERS    100000
#define N_ENTITIES 200000
#define N_EDGES    1000000
#define NNZ        1000000
#define CDIM       64
#define N_FACTORS  4
#define N_REL      10
#define TEMP       0.2f

#define CB         1024
#define NBE        196      // ceil(200000/1024)
#define NBU        98       // ceil(100000/1024)
#define ACHUNK     4096
#define GA         245      // ceil(1e6/4096)
#define GCVT       6250     // (200000*64/8)/256
#define KG_BLOCKS  6250     // 200000 / 32 rows per block
#define USER_BLOCKS 3125    // 100000 / 32
#define PCHUNK     4096
#define GPE        49       // ceil(200000/4096)
#define GPU_       25       // ceil(100000/4096)

typedef unsigned int u32;
typedef unsigned short u16;

__device__ __forceinline__ float bflo(u32 w) { return __uint_as_float(w << 16); }
__device__ __forceinline__ float bfhi(u32 w) { return __uint_as_float(w & 0xFFFF0000u); }
__device__ __forceinline__ u16 f2bf(float f) {
    u32 u = __float_as_uint(f);
    u32 r = u + 0x7FFFu + ((u >> 16) & 1u);   // RNE
    return (u16)(r >> 16);
}
__device__ __forceinline__ void unpack8(uint4 rv, float* x) {
    x[0] = bflo(rv.x); x[1] = bfhi(rv.x);
    x[2] = bflo(rv.y); x[3] = bfhi(rv.y);
    x[4] = bflo(rv.z); x[5] = bfhi(rv.z);
    x[6] = bflo(rv.w); x[7] = bfhi(rv.w);
}
__device__ __forceinline__ uint4 pack8(const float* x) {
    uint4 o;
    o.x = (u32)f2bf(x[0]) | ((u32)f2bf(x[1]) << 16);
    o.y = (u32)f2bf(x[2]) | ((u32)f2bf(x[3]) << 16);
    o.z = (u32)f2bf(x[4]) | ((u32)f2bf(x[5]) << 16);
    o.w = (u32)f2bf(x[6]) | ((u32)f2bf(x[7]) << 16);
    return o;
}
__device__ __forceinline__ void fma_rowW(float* acc, uint4 rv, int rel,
                                         const float* __restrict__ weight, int seg) {
    float x[8]; unpack8(rv, x);
    const float4* wp = (const float4*)(weight + rel * CDIM + seg * 8);
    float4 w0 = wp[0], w1 = wp[1];
    acc[0] += x[0] * w0.x; acc[1] += x[1] * w0.y;
    acc[2] += x[2] * w0.z; acc[3] += x[3] * w0.w;
    acc[4] += x[4] * w1.x; acc[5] += x[5] * w1.y;
    acc[6] += x[6] * w1.z; acc[7] += x[7] * w1.w;
}
__device__ __forceinline__ void fma_rowV(float* acc, uint4 rv, float v) {
    float x[8]; unpack8(rv, x);
    #pragma unroll
    for (int k = 0; k < 8; ++k) acc[k] += v * x[k];
}

// ============ kernel A: cvt + 2x coarse hist + disen/cor =====================
__device__ void dev_cvt(int b, const float* __restrict__ in, u16* __restrict__ out) {
    int i = b * 256 + threadIdx.x;            // i < GCVT*256 == n8 exactly
    const float4* p = (const float4*)(in + (size_t)i * 8);
    float4 a = p[0], bb = p[1];
    float x[8] = {a.x, a.y, a.z, a.w, bb.x, bb.y, bb.z, bb.w};
    *(uint4*)(out + (size_t)i * 8) = pack8(x);
}

__device__ void dev_coarse_hist(int b, const int* __restrict__ idx, int n,
                                int* __restrict__ bhist) {
    __shared__ int lh[256];
    int t = threadIdx.x;
    lh[t] = 0; __syncthreads();
    int base = b * ACHUNK;
    #pragma unroll
    for (int k = 0; k < 16; ++k) {
        int i = base + k * 256 + t;
        if (i < n) atomicAdd(&lh[idx[i] >> 10], 1);
    }
    __syncthreads();
    if (lh[t]) atomicAdd(&bhist[t], lh[t]);
}

__device__ void dev_disen_cor(const float* __restrict__ att,
                              const float* __restrict__ weight,
                              float* __restrict__ dw, float* __restrict__ cor_out) {
    int tid = threadIdx.x;
    int f = tid >> 6, c = tid & 63;
    float m = -1e30f;
    for (int r = 0; r < N_REL; ++r) m = fmaxf(m, att[f * N_REL + r]);
    float e[N_REL], s = 0.0f;
    for (int r = 0; r < N_REL; ++r) { e[r] = __expf(att[f * N_REL + r] - m); s += e[r]; }
    float acc = 0.0f;
    for (int r = 0; r < N_REL; ++r) acc += (e[r] / s) * weight[r * CDIM + c];
    dw[f * CDIM + c] = acc;

    if (tid == 0) {
        float rowsum[N_FACTORS];
        for (int ff = 0; ff < N_FACTORS; ++ff) {
            float ss = 0.0f;
            for (int j = 0; j < N_REL; ++j) ss += att[ff * N_REL + j];
            rowsum[ff] = ss;
        }
        float cor = 0.0f;
        for (int i = 0; i < N_REL; ++i) {
            float nsq = 0.0f, ttl = 0.0f;
            for (int ff = 0; ff < N_FACTORS; ++ff) {
                float a = att[ff * N_REL + i];
                nsq += a * a;
                ttl += a * rowsum[ff];
            }
            float n = sqrtf(nsq);
            float pos = 0.0f;
            for (int ff = 0; ff < N_FACTORS; ++ff) {
                float a = att[ff * N_REL + i] / n;
                pos += a * a;
            }
            cor += (ttl - pos) / TEMP;
        }
        *cor_out = cor;
    }
}

__global__ __launch_bounds__(256) void prep_kernel(const float* __restrict__ entity_emb,
                                                   u16* __restrict__ ebf,
                                                   const int* __restrict__ head,
                                                   const int* __restrict__ inter_rows,
                                                   int* __restrict__ bhe,
                                                   int* __restrict__ bhu,
                                                   const float* __restrict__ att,
                                                   const float* __restrict__ weight,
                                                   float* __restrict__ dw,
                                                   float* __restrict__ cor_out) {
    int bid = blockIdx.x;
    if (bid < GCVT)                 dev_cvt(bid, entity_emb, ebf);
    else if (bid < GCVT + GA)       dev_coarse_hist(bid - GCVT, head, N_EDGES, bhe);
    else if (bid < GCVT + 2 * GA)   dev_coarse_hist(bid - GCVT - GA, inter_rows, NNZ, bhu);
    else                            dev_disen_cor(att, weight, dw, cor_out);
}

// ============ kernel B: two bucket scans (2 blocks) ==========================
__device__ void dev_bucket_scan(const int* __restrict__ bhist, int nb,
                                int* __restrict__ bbase, int* __restrict__ gcur,
                                int* __restrict__ off_n) {
    __shared__ int s[256];
    int t = threadIdx.x;
    int v = (t < nb) ? bhist[t] : 0;
    s[t] = v; __syncthreads();
    #pragma unroll
    for (int d = 1; d < 256; d <<= 1) {
        int x = (t >= d) ? s[t - d] : 0;
        __syncthreads();
        s[t] += x;
        __syncthreads();
    }
    int excl = s[t] - v;
    if (t < nb) { bbase[t] = excl; gcur[t] = excl; }
    if (t == nb - 1) { bbase[nb] = s[t]; *off_n = s[t]; }
}

__global__ __launch_bounds__(256) void bucket_scan2(const int* __restrict__ bhe,
                                                    const int* __restrict__ bhu,
                                                    int* __restrict__ bbe, int* __restrict__ bbu,
                                                    int* __restrict__ gce, int* __restrict__ gcu,
                                                    int* __restrict__ eoffN, int* __restrict__ uoffN) {
    if (blockIdx.x == 0) dev_bucket_scan(bhe, NBE, bbe, gce, eoffN);
    else                 dev_bucket_scan(bhu, NBU, bbu, gcu, uoffN);
}

// ============ kernel C: bin passes ==========================================
__device__ void dev_bin_edges(int b, const int* __restrict__ head,
                              const int* __restrict__ tail, const int* __restrict__ etype,
                              int* __restrict__ gcur, int* __restrict__ binbuf) {
    __shared__ int lh[256], lbase[256];
    int t = threadIdx.x;
    lh[t] = 0; __syncthreads();
    int base = b * ACHUNK;
    int rec[16], rnk[16], bkt[16];
    #pragma unroll
    for (int k = 0; k < 16; ++k) {
        int i = base + k * 256 + t;
        rnk[k] = -1; rec[k] = 0; bkt[k] = 0;
        if (i < N_EDGES) {
            int h = head[i];
            bkt[k] = h >> 10;
            rec[k] = ((h & 1023) << 22) | ((etype[i] - 1) << 18) | tail[i];
            rnk[k] = atomicAdd(&lh[bkt[k]], 1);
        }
    }
    __syncthreads();
    lbase[t] = lh[t] ? atomicAdd(&gcur[t], lh[t]) : 0;
    __syncthreads();
    #pragma unroll
    for (int k = 0; k < 16; ++k)
        if (rnk[k] >= 0) binbuf[lbase[bkt[k]] + rnk[k]] = rec[k];
}

__device__ void dev_bin_inter(int b, const int* __restrict__ rows,
                              const int* __restrict__ cols, const float* __restrict__ vals,
                              int* __restrict__ gcur, int2* __restrict__ binbuf) {
    __shared__ int lh[256], lbase[256];
    int t = threadIdx.x;
    lh[t] = 0; __syncthreads();
    int base = b * ACHUNK;
    int recx[16], recy[16], rnk[16], bkt[16];
    #pragma unroll
    for (int k = 0; k < 16; ++k) {
        int i = base + k * 256 + t;
        rnk[k] = -1; recx[k] = 0; recy[k] = 0; bkt[k] = 0;
        if (i < NNZ) {
            int r = rows[i];
            bkt[k] = r >> 10;
            recx[k] = ((r & 1023) << 18) | cols[i];
            recy[k] = __float_as_int(vals[i]);
            rnk[k] = atomicAdd(&lh[bkt[k]], 1);
        }
    }
    __syncthreads();
    lbase[t] = lh[t] ? atomicAdd(&gcur[t], lh[t]) : 0;
    __syncthreads();
    #pragma unroll
    for (int k = 0; k < 16; ++k)
        if (rnk[k] >= 0) {
            int2 p; p.x = recx[k]; p.y = recy[k];
            binbuf[lbase[bkt[k]] + rnk[k]] = p;
        }
}

__global__ __launch_bounds__(256) void bin_kernel(const int* __restrict__ head,
                                                  const int* __restrict__ tail,
                                                  const int* __restrict__ etype,
                                                  const int* __restrict__ rows,
                                                  const int* __restrict__ cols,
                                                  const float* __restrict__ vals,
                                                  int* __restrict__ gce, int* __restrict__ gcu,
                                                  int* __restrict__ bine, int2* __restrict__ binu) {
    int bid = blockIdx.x;
    if (bid < GA) dev_bin_edges(bid, head, tail, etype, gce, bine);
    else          dev_bin_inter(bid - GA, rows, cols, vals, gcu, binu);
}

// ============ kernel D: per-bucket CSR finalize + degree histogram ===========
__device__ void dev_build_e(int b, const int* __restrict__ bbase,
                            const int* __restrict__ binbuf,
                            int* __restrict__ eoff, int* __restrict__ epk,
                            int* __restrict__ dbinE) {
    __shared__ int lh[CB];
    __shared__ int ss[256];
    __shared__ int ldeg[64];
    int t = threadIdx.x;
    int bstart = bbase[b], bend = bbase[b + 1];
    #pragma unroll
    for (int k = 0; k < 4; ++k) lh[t * 4 + k] = 0;
    if (t < 64) ldeg[t] = 0;
    __syncthreads();
    for (int j = bstart + t; j < bend; j += 256)
        atomicAdd(&lh[(u32)binbuf[j] >> 22], 1);
    __syncthreads();
    int v[4], acc = 0;
    #pragma unroll
    for (int k = 0; k < 4; ++k) { v[k] = lh[t * 4 + k]; acc += v[k]; }
    ss[t] = acc; __syncthreads();
    #pragma unroll
    for (int d = 1; d < 256; d <<= 1) {
        int x = (t >= d) ? ss[t - d] : 0;
        __syncthreads();
        ss[t] += x;
        __syncthreads();
    }
    int excl = ss[t] - acc;
    int hbase = b * CB;
    #pragma unroll
    for (int k = 0; k < 4; ++k) {
        int hl = t * 4 + k;
        int h = hbase + hl;
        if (h < N_ENTITIES) {
            eoff[h] = bstart + excl;
            atomicAdd(&ldeg[63 - min(v[k], 63)], 1);   // descending-degree bins
        }
        lh[hl] = excl;
        excl += v[k];
    }
    __syncthreads();
    if (t < 64 && ldeg[t]) atomicAdd(&dbinE[t], ldeg[t]);
    for (int j = bstart + t; j < bend; j += 256) {
        int rec = binbuf[j];
        int pos = atomicAdd(&lh[(u32)rec >> 22], 1);
        epk[bstart + pos] = rec & 0x3FFFFF;   // rel<<18 | tail
    }
}

__device__ void dev_build_u(int b, const int* __restrict__ bbase,
                            const int2* __restrict__ binbuf,
                            int* __restrict__ uoff, int2* __restrict__ ucv,
                            int* __restrict__ dbinU) {
    __shared__ int lh[CB];
    __shared__ int ss[256];
    __shared__ int ldeg[64];
    int t = threadIdx.x;
    int bstart = bbase[b], bend = bbase[b + 1];
    #pragma unroll
    for (int k = 0; k < 4; ++k) lh[t * 4 + k] = 0;
    if (t < 64) ldeg[t] = 0;
    __syncthreads();
    for (int j = bstart + t; j < bend; j += 256)
        atomicAdd(&lh[(u32)binbuf[j].x >> 18], 1);
    __syncthreads();
    int v[4], acc = 0;
    #pragma unroll
    for (int k = 0; k < 4; ++k) { v[k] = lh[t * 4 + k]; acc += v[k]; }
    ss[t] = acc; __syncthreads();
    #pragma unroll
    for (int d = 1; d < 256; d <<= 1) {
        int x = (t >= d) ? ss[t - d] : 0;
        __syncthreads();
        ss[t] += x;
        __syncthreads();
    }
    int excl = ss[t] - acc;
    int ubase = b * CB;
    #pragma unroll
    for (int k = 0; k < 4; ++k) {
        int ul = t * 4 + k;
        int u = ubase + ul;
        if (u < N_USERS) {
            uoff[u] = bstart + excl;
            atomicAdd(&ldeg[63 - min(v[k], 63)], 1);
        }
        lh[ul] = excl;
        excl += v[k];
    }
    __syncthreads();
    if (t < 64 && ldeg[t]) atomicAdd(&dbinU[t], ldeg[t]);
    for (int j = bstart + t; j < bend; j += 256) {
        int2 rec = binbuf[j];
        int pos = atomicAdd(&lh[(u32)rec.x >> 18], 1);
        int2 out; out.x = rec.x & 0x3FFFF; out.y = rec.y;
        ucv[bstart + pos] = out;
    }
}

__global__ __launch_bounds__(256) void build_kernel(const int* __restrict__ bbe,
                                                    const int* __restrict__ bbu,
                                                    const int* __restrict__ bine,
                                                    const int2* __restrict__ binu,
                                                    int* __restrict__ eoff, int* __restrict__ epk,
                                                    int* __restrict__ uoff, int2* __restrict__ ucv,
                                                    int* __restrict__ dbinE, int* __restrict__ dbinU) {
    int bid = blockIdx.x;
    if (bid < NBE) dev_build_e(bid, bbe, bine, eoff, epk, dbinE);
    else           dev_build_u(bid - NBE, bbu, binu, uoff, ucv, dbinU);
}

// ============ kernel E: degree-bin scan (1 block) ============================
__global__ void deg_scan(const int* __restrict__ dbinE, const int* __restrict__ dbinU,
                         int* __restrict__ curE, int* __restrict__ curU) {
    int t = threadIdx.x;
    if (t == 0) { int run = 0; for (int b = 0; b < 64; ++b) { curE[b] = run; run += dbinE[b]; } }
    if (t == 1) { int run = 0; for (int b = 0; b < 64; ++b) { curU[b] = run; run += dbinU[b]; } }
}

// ============ kernel F: degree-sorted permutation ============================
__device__ void dev_perm(int b, int n, const int* __restrict__ off,
                         int* __restrict__ gcur, int2* __restrict__ perm) {
    __shared__ int lh[64], lbase[64];
    int t = threadIdx.x;
    if (t < 64) lh[t] = 0;
    __syncthreads();
    int base = b * PCHUNK;
    int rnk[16], bin[16], deg[16], st[16];
    #pragma unroll
    for (int k = 0; k < 16; ++k) {
        int i = base + k * 256 + t;
        rnk[k] = -1;
        if (i < n) {
            int s0 = off[i], s1 = off[i + 1];
            deg[k] = s1 - s0; st[k] = s0;
            bin[k] = 63 - min(deg[k], 63);     // descending degree
            rnk[k] = atomicAdd(&lh[bin[k]], 1);
        }
    }
    __syncthreads();
    if (t < 64) lbase[t] = lh[t] ? atomicAdd(&gcur[t], lh[t]) : 0;
    __syncthreads();
    #pragma unroll
    for (int k = 0; k < 16; ++k)
        if (rnk[k] >= 0) {
            int i = base + k * 256 + t;
            int2 p;
            p.x = (int)(((u32)min(deg[k], 16383) << 18) | (u32)i);
            p.y = st[k];
            perm[lbase[bin[k]] + rnk[k]] = p;
        }
}

__global__ __launch_bounds__(256) void perm_kernel(const int* __restrict__ eoff,
                                                   const int* __restrict__ uoff,
                                                   int* __restrict__ curE, int* __restrict__ curU,
                                                   int2* __restrict__ permE, int2* __restrict__ permU) {
    int bid = blockIdx.x;
    if (bid < GPE) dev_perm(bid, N_ENTITIES, eoff, curE, permE);
    else           dev_perm(bid - GPE, N_USERS, uoff, curU, permU);
}

// ============ hop kernels (kg + user merged), 4-deep pipelined gather ========
__device__ void dev_kg_hop(int widg, const u16* __restrict__ esrc,
                           const int2* __restrict__ permE,
                           const int* __restrict__ epk,
                           const float* __restrict__ weight,
                           const float* __restrict__ emb0,
                           u16* __restrict__ enew, float* __restrict__ eres, int last) {
    int lane = threadIdx.x & 63;
    int slot = lane >> 3, seg = lane & 7;
    int2 pe = permE[widg * 8 + slot];
    u32 px = (u32)pe.x;
    int d = px >> 18, h = (int)(px & 0x3FFFFu), s = pe.y;
    int dmax = d;
    dmax = max(dmax, __shfl_xor(dmax, 8, 64));
    dmax = max(dmax, __shfl_xor(dmax, 16, 64));
    dmax = max(dmax, __shfl_xor(dmax, 32, 64));

    float acc[8];
    #pragma unroll
    for (int k = 0; k < 8; ++k) acc[k] = 0.0f;
    const uint4 uz = make_uint4(0u, 0u, 0u, 0u);

    for (int it = 0; it < dmax; it += 4) {
        int p0 = (it     < d) ? epk[s + it]     : 0;
        int p1 = (it + 1 < d) ? epk[s + it + 1] : 0;
        int p2 = (it + 2 < d) ? epk[s + it + 2] : 0;
        int p3 = (it + 3 < d) ? epk[s + it + 3] : 0;
        uint4 rv0 = (it     < d) ? *(const uint4*)(esrc + (size_t)(p0 & 0x3FFFF) * CDIM + seg * 8) : uz;
        uint4 rv1 = (it + 1 < d) ? *(const uint4*)(esrc + (size_t)(p1 & 0x3FFFF) * CDIM + seg * 8) : uz;
        uint4 rv2 = (it + 2 < d) ? *(const uint4*)(esrc + (size_t)(p2 & 0x3FFFF) * CDIM + seg * 8) : uz;
        uint4 rv3 = (it + 3 < d) ? *(const uint4*)(esrc + (size_t)(p3 & 0x3FFFF) * CDIM + seg * 8) : uz;
        fma_rowW(acc, rv0, p0 >> 18, weight, seg);
        fma_rowW(acc, rv1, p1 >> 18, weight, seg);
        fma_rowW(acc, rv2, p2 >> 18, weight, seg);
        fma_rowW(acc, rv3, p3 >> 18, weight, seg);
    }
    float inv = 1.0f / fmaxf((float)d, 1.0f);
    float ssq = 0.0f;
    #pragma unroll
    for (int k = 0; k < 8; ++k) { acc[k] *= inv; ssq += acc[k] * acc[k]; }
    ssq += __shfl_xor(ssq, 1, 64);
    ssq += __shfl_xor(ssq, 2, 64);
    ssq += __shfl_xor(ssq, 4, 64);
    float rn = 1.0f / fmaxf(sqrtf(ssq), 1e-12f);
    #pragma unroll
    for (int k = 0; k < 8; ++k) acc[k] *= rn;

    size_t base = (size_t)h * CDIM + seg * 8;
    if (!last) {
        *(uint4*)(enew + base) = pack8(acc);
    } else {
        uint4 pv = *(const uint4*)(esrc + base);   // esrc == hop0 output eA
        float o0[8]; unpack8(pv, o0);
        float4 a = *(const float4*)(emb0 + base);
        float4 b = *(const float4*)(emb0 + base + 4);
        float4 r0, r1;
        r0.x = a.x + o0[0] + acc[0]; r0.y = a.y + o0[1] + acc[1];
        r0.z = a.z + o0[2] + acc[2]; r0.w = a.w + o0[3] + acc[3];
        r1.x = b.x + o0[4] + acc[4]; r1.y = b.y + o0[5] + acc[5];
        r1.z = b.z + o0[6] + acc[6]; r1.w = b.w + o0[7] + acc[7];
        *(float4*)(eres + base) = r0;
        *(float4*)(eres + base + 4) = r1;
    }
}

__device__ void dev_user_hop(int widg, const float* __restrict__ uoldf,
                             const u16* __restrict__ uoldb,
                             const u16* __restrict__ esrc,
                             const int2* __restrict__ permU,
                             const int2* __restrict__ ucv,
                             const float* __restrict__ latent,
                             const float* __restrict__ dw,
                             const float* __restrict__ uemb0,
                             u16* __restrict__ unew, float* __restrict__ ures, int last) {
    int lane = threadIdx.x & 63;
    int slot = lane >> 3, seg = lane & 7;
    int2 pe = permU[widg * 8 + slot];
    u32 px = (u32)pe.x;
    int d = px >> 18, u = (int)(px & 0x3FFFFu), s = pe.y;
    int dmax = d;
    dmax = max(dmax, __shfl_xor(dmax, 8, 64));
    dmax = max(dmax, __shfl_xor(dmax, 16, 64));
    dmax = max(dmax, __shfl_xor(dmax, 32, 64));

    float acc[8];
    #pragma unroll
    for (int k = 0; k < 8; ++k) acc[k] = 0.0f;
    const uint4 uz = make_uint4(0u, 0u, 0u, 0u);
    const int2 cz = make_int2(0, 0);

    for (int it = 0; it < dmax; it += 4) {
        int2 c0 = (it     < d) ? ucv[s + it]     : cz;
        int2 c1 = (it + 1 < d) ? ucv[s + it + 1] : cz;
        int2 c2 = (it + 2 < d) ? ucv[s + it + 2] : cz;
        int2 c3 = (it + 3 < d) ? ucv[s + it + 3] : cz;
        uint4 rv0 = (it     < d) ? *(const uint4*)(esrc + (size_t)c0.x * CDIM + seg * 8) : uz;
        uint4 rv1 = (it + 1 < d) ? *(const uint4*)(esrc + (size_t)c1.x * CDIM + seg * 8) : uz;
        uint4 rv2 = (it + 2 < d) ? *(const uint4*)(esrc + (size_t)c2.x * CDIM + seg * 8) : uz;
        uint4 rv3 = (it + 3 < d) ? *(const uint4*)(esrc + (size_t)c3.x * CDIM + seg * 8) : uz;
        fma_rowV(acc, rv0, __int_as_float(c0.y));
        fma_rowV(acc, rv1, __int_as_float(c1.y));
        fma_rowV(acc, rv2, __int_as_float(c2.y));
        fma_rowV(acc, rv3, __int_as_float(c3.y));
    }

    float uo[8];
    size_t ubase = (size_t)u * CDIM + seg * 8;
    if (uoldb) {
        uint4 pv = *(const uint4*)(uoldb + ubase);
        unpack8(pv, uo);
    } else {
        float4 a = *(const float4*)(uoldf + ubase);
        float4 b = *(const float4*)(uoldf + ubase + 4);
        uo[0] = a.x; uo[1] = a.y; uo[2] = a.z; uo[3] = a.w;
        uo[4] = b.x; uo[5] = b.y; uo[6] = b.z; uo[7] = b.w;
    }
    float dts[N_FACTORS];
    #pragma unroll
    for (int f = 0; f < N_FACTORS; ++f) {
        const float4* lp = (const float4*)(latent + f * CDIM + seg * 8);
        float4 l0 = lp[0], l1 = lp[1];
        float p = uo[0] * l0.x + uo[1] * l0.y + uo[2] * l0.z + uo[3] * l0.w +
                  uo[4] * l1.x + uo[5] * l1.y + uo[6] * l1.z + uo[7] * l1.w;
        p += __shfl_xor(p, 1, 64);
        p += __shfl_xor(p, 2, 64);
        p += __shfl_xor(p, 4, 64);
        dts[f] = p;
    }
    float m = fmaxf(fmaxf(dts[0], dts[1]), fmaxf(dts[2], dts[3]));
    float e0 = __expf(dts[0] - m), e1 = __expf(dts[1] - m);
    float e2 = __expf(dts[2] - m), e3 = __expf(dts[3] - m);
    float inv_ssum = 1.0f / (e0 + e1 + e2 + e3);
    e0 *= inv_ssum; e1 *= inv_ssum; e2 *= inv_ssum; e3 *= inv_ssum;

    const float4* d0p = (const float4*)(dw + 0 * CDIM + seg * 8);
    const float4* d1p = (const float4*)(dw + 1 * CDIM + seg * 8);
    const float4* d2p = (const float4*)(dw + 2 * CDIM + seg * 8);
    const float4* d3p = (const float4*)(dw + 3 * CDIM + seg * 8);
    float4 ga0 = d0p[0], ga1 = d0p[1];
    float4 gb0 = d1p[0], gb1 = d1p[1];
    float4 gc0 = d2p[0], gc1 = d2p[1];
    float4 gd0 = d3p[0], gd1 = d3p[1];
    float g[8];
    g[0] = e0 * ga0.x + e1 * gb0.x + e2 * gc0.x + e3 * gd0.x;
    g[1] = e0 * ga0.y + e1 * gb0.y + e2 * gc0.y + e3 * gd0.y;
    g[2] = e0 * ga0.z + e1 * gb0.z + e2 * gc0.z + e3 * gd0.z;
    g[3] = e0 * ga0.w + e1 * gb0.w + e2 * gc0.w + e3 * gd0.w;
    g[4] = e0 * ga1.x + e1 * gb1.x + e2 * gc1.x + e3 * gd1.x;
    g[5] = e0 * ga1.y + e1 * gb1.y + e2 * gc1.y + e3 * gd1.y;
    g[6] = e0 * ga1.z + e1 * gb1.z + e2 * gc1.z + e3 * gd1.z;
    g[7] = e0 * ga1.w + e1 * gb1.w + e2 * gc1.w + e3 * gd1.w;

    float ssq = 0.0f;
    #pragma unroll
    for (int k = 0; k < 8; ++k) {
        acc[k] = acc[k] * (1.0f + g[k]);
        ssq += acc[k] * acc[k];
    }
    ssq += __shfl_xor(ssq, 1, 64);
    ssq += __shfl_xor(ssq, 2, 64);
    ssq += __shfl_xor(ssq, 4, 64);
    float rn = 1.0f / fmaxf(sqrtf(ssq), 1e-12f);
    #pragma unroll
    for (int k = 0; k < 8; ++k) acc[k] *= rn;

    if (!last) {
        *(uint4*)(unew + ubase) = pack8(acc);
    } else {
        float4 a = *(const float4*)(uemb0 + ubase);
        float4 b = *(const float4*)(uemb0 + ubase + 4);
        float4 r0, r1;
        r0.x = a.x + uo[0] + acc[0]; r0.y = a.y + uo[1] + acc[1];
        r0.z = a.z + uo[2] + acc[2]; r0.w = a.w + uo[3] + acc[3];
        r1.x = b.x + uo[4] + acc[4]; r1.y = b.y + uo[5] + acc[5];
        r1.z = b.z + uo[6] + acc[6]; r1.w = b.w + uo[7] + acc[7];
        *(float4*)(ures + ubase) = r0;
        *(float4*)(ures + ubase + 4) = r1;
    }
}

__global__ __launch_bounds__(256) void hop_kernel(const u16* __restrict__ e_src,
                                                  const int2* __restrict__ permE,
                                                  const int* __restrict__ epk,
                                                  const float* __restrict__ weight,
                                                  const float* __restrict__ entity_emb,
                                                  u16* __restrict__ eA,
                                                  float* __restrict__ eres,
                                                  const float* __restrict__ uoldf,
                                                  const u16* __restrict__ uoldb,
                                                  const int2* __restrict__ permU,
                                                  const int2* __restrict__ ucv,
                                                  const float* __restrict__ latent,
                                                  const float* __restrict__ dw,
                                                  const float* __restrict__ user_emb,
                                                  u16* __restrict__ uA,
                                                  float* __restrict__ ures,
                                                  int last) {
    int bid = blockIdx.x;
    int wave = threadIdx.x >> 6;
    if (bid < KG_BLOCKS) {
        dev_kg_hop(bid * 4 + wave, e_src, permE, epk, weight, entity_emb, eA, eres, last);
    } else {
        dev_user_hop((bid - KG_BLOCKS) * 4 + wave, uoldf, uoldb, e_src, permU, ucv,
                     latent, dw, user_emb, uA, ures, last);
    }
}

static inline size_t align16(size_t x) { return (x + 15) & ~(size_t)15; }

extern "C" void kernel_launch(void* const* d_in, const int* in_sizes, int n_in,
                              void* d_out, int out_size, void* d_ws, size_t ws_size,
                              hipStream_t stream) {
    const float* user_emb   = (const float*)d_in[0];
    const float* entity_emb = (const float*)d_in[1];
    const float* latent_emb = (const float*)d_in[2];
    const float* weight     = (const float*)d_in[3];
    const float* att        = (const float*)d_in[4];
    const int*   edge_index = (const int*)d_in[5];
    const int*   edge_type  = (const int*)d_in[6];
    const int*   inter_rows = (const int*)d_in[7];
    const int*   inter_cols = (const int*)d_in[8];
    const float* inter_vals = (const float*)d_in[9];

    float* eres = (float*)d_out;
    float* ures = eres + (size_t)N_ENTITIES * CDIM;
    float* cor  = ures + (size_t)N_USERS * CDIM;

    char* ws = (char*)d_ws;
    u16*   ebf   = (u16*)ws;  ws += align16(sizeof(u16) * (size_t)N_ENTITIES * CDIM);
    u16*   eA    = (u16*)ws;  ws += align16(sizeof(u16) * (size_t)N_ENTITIES * CDIM);
    u16*   uA    = (u16*)ws;  ws += align16(sizeof(u16) * (size_t)N_USERS * CDIM);
    int*   eoff  = (int*)ws;  ws += align16(sizeof(int) * (N_ENTITIES + 1));
    int*   epk   = (int*)ws;  ws += align16(sizeof(int) * N_EDGES);
    int*   uoff  = (int*)ws;  ws += align16(sizeof(int) * (N_USERS + 1));
    int2*  ucv   = (int2*)ws; ws += align16(sizeof(int2) * NNZ);
    int*   bine  = (int*)ws;  ws += align16(sizeof(int) * N_EDGES);
    int2*  binu  = (int2*)ws; ws += align16(sizeof(int2) * NNZ);
    int*   ctrs  = (int*)ws;  ws += align16(sizeof(int) * 640);   // bhe256|bhu256|dbinE64|dbinU64
    int*   bbe   = (int*)ws;  ws += align16(sizeof(int) * 257);
    int*   bbu   = (int*)ws;  ws += align16(sizeof(int) * 257);
    int*   gce   = (int*)ws;  ws += align16(sizeof(int) * 256);
    int*   gcu   = (int*)ws;  ws += align16(sizeof(int) * 256);
    int*   curE  = (int*)ws;  ws += align16(sizeof(int) * 64);
    int*   curU  = (int*)ws;  ws += align16(sizeof(int) * 64);
    int2*  permE = (int2*)ws; ws += align16(sizeof(int2) * N_ENTITIES);
    int2*  permU = (int2*)ws; ws += align16(sizeof(int2) * N_USERS);
    float* dw    = (float*)ws; ws += align16(sizeof(float) * N_FACTORS * CDIM);

    int* bhe   = ctrs;
    int* bhu   = ctrs + 256;
    int* dbinE = ctrs + 512;
    int* dbinU = ctrs + 576;

    const int* head = edge_index;
    const int* tail = edge_index + N_EDGES;

    (void)hipMemsetAsync(ctrs, 0, sizeof(int) * 640, stream);

    prep_kernel<<<GCVT + 2 * GA + 1, 256, 0, stream>>>(entity_emb, ebf, head, inter_rows,
                                                       bhe, bhu, att, weight, dw, cor);
    bucket_scan2<<<2, 256, 0, stream>>>(bhe, bhu, bbe, bbu, gce, gcu,
                                        eoff + N_ENTITIES, uoff + N_USERS);
    bin_kernel<<<2 * GA, 256, 0, stream>>>(head, tail, edge_type,
                                           inter_rows, inter_cols, inter_vals,
                                           gce, gcu, bine, binu);
    build_kernel<<<NBE + NBU, 256, 0, stream>>>(bbe, bbu, bine, binu,
                                                eoff, epk, uoff, ucv, dbinE, dbinU);
    deg_scan<<<1, 64, 0, stream>>>(dbinE, dbinU, curE, curU);
    perm_kernel<<<GPE + GPU_, 256, 0, stream>>>(eoff, uoff, curE, curU, permE, permU);

    // hop 0: gather from ebf; write bf16 eA/uA
    hop_kernel<<<KG_BLOCKS + USER_BLOCKS, 256, 0, stream>>>(
        ebf, permE, epk, weight, entity_emb, eA, eres,
        user_emb, (const u16*)nullptr, permU, ucv, latent_emb, dw, user_emb, uA, ures, 0);
    // hop 1: gather from eA/uA; write res = emb0 + o0 + o1
    hop_kernel<<<KG_BLOCKS + USER_BLOCKS, 256, 0, stream>>>(
        eA, permE, epk, weight, entity_emb, (u16*)nullptr, eres,
        (const float*)nullptr, uA, permU, ucv, latent_emb, dw, user_emb, (u16*)nullptr, ures, 1);
}

// Round 10
// 216.013 us; speedup vs baseline: 5.4573x; 1.2410x over previous
//
#include <hip/hip_runtime.h>
#include <math.h>

#define N_USERS    100000
#define N_ENTITIES 200000
#define N_EDGES    1000000
#define NNZ        1000000
#define CDIM       64
#define N_FACTORS  4
#define N_REL      10
#define TEMP       0.2f

#define CB         1024
#define NBE        196      // ceil(200000/1024)
#define NBU        98       // ceil(100000/1024)
#define ACHUNK     4096
#define GA         245      // ceil(1e6/4096)
#define GCVT       6250     // (200000*64/8)/256
#define KG_BLOCKS  6250     // 200000 / 32 rows per block
#define USER_BLOCKS 3125    // 100000 / 32
#define PCHUNK     4096
#define GPE        49       // ceil(200000/4096)
#define GPU_       25       // ceil(100000/4096)

typedef unsigned int u32;
typedef unsigned short u16;
typedef unsigned char u8;

#if defined(__has_builtin)
#if __has_builtin(__builtin_amdgcn_cvt_pk_f32_fp8) && __has_builtin(__builtin_amdgcn_cvt_pk_fp8_f32)
#define HAVE_HW_FP8 1
#endif
#endif

// ---- bf16 helpers ----------------------------------------------------------
__device__ __forceinline__ float bflo(u32 w) { return __uint_as_float(w << 16); }
__device__ __forceinline__ float bfhi(u32 w) { return __uint_as_float(w & 0xFFFF0000u); }
__device__ __forceinline__ u16 f2bf(float f) {
    u32 u = __float_as_uint(f);
    u32 r = u + 0x7FFFu + ((u >> 16) & 1u);   // RNE
    return (u16)(r >> 16);
}
__device__ __forceinline__ void unpack8_bf(uint4 rv, float* x) {
    x[0] = bflo(rv.x); x[1] = bfhi(rv.x);
    x[2] = bflo(rv.y); x[3] = bfhi(rv.y);
    x[4] = bflo(rv.z); x[5] = bfhi(rv.z);
    x[6] = bflo(rv.w); x[7] = bfhi(rv.w);
}
__device__ __forceinline__ uint4 pack8_bf(const float* x) {
    uint4 o;
    o.x = (u32)f2bf(x[0]) | ((u32)f2bf(x[1]) << 16);
    o.y = (u32)f2bf(x[2]) | ((u32)f2bf(x[3]) << 16);
    o.z = (u32)f2bf(x[4]) | ((u32)f2bf(x[5]) << 16);
    o.w = (u32)f2bf(x[6]) | ((u32)f2bf(x[7]) << 16);
    return o;
}

// ---- fp8 e4m3 helpers ------------------------------------------------------
#ifndef HAVE_HW_FP8
__device__ __forceinline__ float fp8_dec1(u32 b) {
    u32 s = b >> 7, em = b & 0x7F;
    float mag;
    if (em < 8) mag = (float)em * 0.001953125f;                      // subnormal, 2^-9
    else {
        u32 bits = (((em >> 3) + 120u) << 23) | ((em & 7u) << 20);
        mag = __uint_as_float(bits);
    }
    return s ? -mag : mag;
}
__device__ __forceinline__ u32 fp8_enc1(float f) {
    float a = fabsf(f);
    u32 s = (__float_as_uint(f) >> 31) << 7;
    if (a < 0.015625f) {
        int n = (int)rintf(a * 512.0f);                              // 0..8
        return s | (u32)n;
    }
    u32 u = __float_as_uint(a);
    u32 r = u + 0x0007FFFFu + ((u >> 20) & 1u);                      // RNE at bit 20
    int ee = (int)((r >> 23) & 0xFF) - 127 + 7;
    if (ee >= 16) return s | 0x7Eu;                                  // clamp to 448
    return s | ((u32)ee << 3) | ((r >> 20) & 7u);
}
#endif

__device__ __forceinline__ void unpack8_fp8(uint2 rv, float* x) {
#ifdef HAVE_HW_FP8
    typedef float floatx2 __attribute__((ext_vector_type(2)));
    floatx2 a0 = __builtin_amdgcn_cvt_pk_f32_fp8(rv.x, false);
    floatx2 a1 = __builtin_amdgcn_cvt_pk_f32_fp8(rv.x, true);
    floatx2 a2 = __builtin_amdgcn_cvt_pk_f32_fp8(rv.y, false);
    floatx2 a3 = __builtin_amdgcn_cvt_pk_f32_fp8(rv.y, true);
    x[0] = a0.x; x[1] = a0.y; x[2] = a1.x; x[3] = a1.y;
    x[4] = a2.x; x[5] = a2.y; x[6] = a3.x; x[7] = a3.y;
#else
    x[0] = fp8_dec1(rv.x & 0xFF);         x[1] = fp8_dec1((rv.x >> 8) & 0xFF);
    x[2] = fp8_dec1((rv.x >> 16) & 0xFF); x[3] = fp8_dec1(rv.x >> 24);
    x[4] = fp8_dec1(rv.y & 0xFF);         x[5] = fp8_dec1((rv.y >> 8) & 0xFF);
    x[6] = fp8_dec1((rv.y >> 16) & 0xFF); x[7] = fp8_dec1(rv.y >> 24);
#endif
}
__device__ __forceinline__ uint2 pack8_fp8(const float* x) {
    uint2 o;
#ifdef HAVE_HW_FP8
    int v0 = 0, v1 = 0;
    v0 = __builtin_amdgcn_cvt_pk_fp8_f32(x[0], x[1], v0, false);
    v0 = __builtin_amdgcn_cvt_pk_fp8_f32(x[2], x[3], v0, true);
    v1 = __builtin_amdgcn_cvt_pk_fp8_f32(x[4], x[5], v1, false);
    v1 = __builtin_amdgcn_cvt_pk_fp8_f32(x[6], x[7], v1, true);
    o.x = (u32)v0; o.y = (u32)v1;
#else
    o.x = fp8_enc1(x[0]) | (fp8_enc1(x[1]) << 8) | (fp8_enc1(x[2]) << 16) | (fp8_enc1(x[3]) << 24);
    o.y = fp8_enc1(x[4]) | (fp8_enc1(x[5]) << 8) | (fp8_enc1(x[6]) << 16) | (fp8_enc1(x[7]) << 24);
#endif
    return o;
}

__device__ __forceinline__ void fma_rowW(float* acc, uint2 rv, int rel,
                                         const float* __restrict__ weight, int seg) {
    float x[8]; unpack8_fp8(rv, x);
    const float4* wp = (const float4*)(weight + rel * CDIM + seg * 8);
    float4 w0 = wp[0], w1 = wp[1];
    acc[0] += x[0] * w0.x; acc[1] += x[1] * w0.y;
    acc[2] += x[2] * w0.z; acc[3] += x[3] * w0.w;
    acc[4] += x[4] * w1.x; acc[5] += x[5] * w1.y;
    acc[6] += x[6] * w1.z; acc[7] += x[7] * w1.w;
}
__device__ __forceinline__ void fma_rowV(float* acc, uint2 rv, float v) {
    float x[8]; unpack8_fp8(rv, x);
    #pragma unroll
    for (int k = 0; k < 8; ++k) acc[k] += v * x[k];
}

// ============ kernel A: cvt(f32->fp8) + 2x coarse hist + disen/cor ===========
__device__ void dev_cvt(int b, const float* __restrict__ in, u8* __restrict__ out) {
    int i = b * 256 + threadIdx.x;            // i < GCVT*256 == n8 exactly
    const float4* p = (const float4*)(in + (size_t)i * 8);
    float4 a = p[0], bb = p[1];
    float x[8] = {a.x, a.y, a.z, a.w, bb.x, bb.y, bb.z, bb.w};
    *(uint2*)(out + (size_t)i * 8) = pack8_fp8(x);
}

__device__ void dev_coarse_hist(int b, const int* __restrict__ idx, int n,
                                int* __restrict__ bhist) {
    __shared__ int lh[256];
    int t = threadIdx.x;
    lh[t] = 0; __syncthreads();
    int base = b * ACHUNK;
    #pragma unroll
    for (int k = 0; k < 16; ++k) {
        int i = base + k * 256 + t;
        if (i < n) atomicAdd(&lh[idx[i] >> 10], 1);
    }
    __syncthreads();
    if (lh[t]) atomicAdd(&bhist[t], lh[t]);
}

__device__ void dev_disen_cor(const float* __restrict__ att,
                              const float* __restrict__ weight,
                              float* __restrict__ dw, float* __restrict__ cor_out) {
    int tid = threadIdx.x;
    int f = tid >> 6, c = tid & 63;
    float m = -1e30f;
    for (int r = 0; r < N_REL; ++r) m = fmaxf(m, att[f * N_REL + r]);
    float e[N_REL], s = 0.0f;
    for (int r = 0; r < N_REL; ++r) { e[r] = __expf(att[f * N_REL + r] - m); s += e[r]; }
    float acc = 0.0f;
    for (int r = 0; r < N_REL; ++r) acc += (e[r] / s) * weight[r * CDIM + c];
    dw[f * CDIM + c] = acc;

    if (tid == 0) {
        float rowsum[N_FACTORS];
        for (int ff = 0; ff < N_FACTORS; ++ff) {
            float ss = 0.0f;
            for (int j = 0; j < N_REL; ++j) ss += att[ff * N_REL + j];
            rowsum[ff] = ss;
        }
        float cor = 0.0f;
        for (int i = 0; i < N_REL; ++i) {
            float nsq = 0.0f, ttl = 0.0f;
            for (int ff = 0; ff < N_FACTORS; ++ff) {
                float a = att[ff * N_REL + i];
                nsq += a * a;
                ttl += a * rowsum[ff];
            }
            float n = sqrtf(nsq);
            float pos = 0.0f;
            for (int ff = 0; ff < N_FACTORS; ++ff) {
                float a = att[ff * N_REL + i] / n;
                pos += a * a;
            }
            cor += (ttl - pos) / TEMP;
        }
        *cor_out = cor;
    }
}

__global__ __launch_bounds__(256) void prep_kernel(const float* __restrict__ entity_emb,
                                                   u8* __restrict__ ef8,
                                                   const int* __restrict__ head,
                                                   const int* __restrict__ inter_rows,
                                                   int* __restrict__ bhe,
                                                   int* __restrict__ bhu,
                                                   const float* __restrict__ att,
                                                   const float* __restrict__ weight,
                                                   float* __restrict__ dw,
                                                   float* __restrict__ cor_out) {
    int bid = blockIdx.x;
    if (bid < GCVT)                 dev_cvt(bid, entity_emb, ef8);
    else if (bid < GCVT + GA)       dev_coarse_hist(bid - GCVT, head, N_EDGES, bhe);
    else if (bid < GCVT + 2 * GA)   dev_coarse_hist(bid - GCVT - GA, inter_rows, NNZ, bhu);
    else                            dev_disen_cor(att, weight, dw, cor_out);
}

// ============ kernel B: two bucket scans (2 blocks) ==========================
__device__ void dev_bucket_scan(const int* __restrict__ bhist, int nb,
                                int* __restrict__ bbase, int* __restrict__ gcur,
                                int* __restrict__ off_n) {
    __shared__ int s[256];
    int t = threadIdx.x;
    int v = (t < nb) ? bhist[t] : 0;
    s[t] = v; __syncthreads();
    #pragma unroll
    for (int d = 1; d < 256; d <<= 1) {
        int x = (t >= d) ? s[t - d] : 0;
        __syncthreads();
        s[t] += x;
        __syncthreads();
    }
    int excl = s[t] - v;
    if (t < nb) { bbase[t] = excl; gcur[t] = excl; }
    if (t == nb - 1) { bbase[nb] = s[t]; *off_n = s[t]; }
}

__global__ __launch_bounds__(256) void bucket_scan2(const int* __restrict__ bhe,
                                                    const int* __restrict__ bhu,
                                                    int* __restrict__ bbe, int* __restrict__ bbu,
                                                    int* __restrict__ gce, int* __restrict__ gcu,
                                                    int* __restrict__ eoffN, int* __restrict__ uoffN) {
    if (blockIdx.x == 0) dev_bucket_scan(bhe, NBE, bbe, gce, eoffN);
    else                 dev_bucket_scan(bhu, NBU, bbu, gcu, uoffN);
}

// ============ kernel C: bin passes ==========================================
__device__ void dev_bin_edges(int b, const int* __restrict__ head,
                              const int* __restrict__ tail, const int* __restrict__ etype,
                              int* __restrict__ gcur, int* __restrict__ binbuf) {
    __shared__ int lh[256], lbase[256];
    int t = threadIdx.x;
    lh[t] = 0; __syncthreads();
    int base = b * ACHUNK;
    int rec[16], rnk[16], bkt[16];
    #pragma unroll
    for (int k = 0; k < 16; ++k) {
        int i = base + k * 256 + t;
        rnk[k] = -1; rec[k] = 0; bkt[k] = 0;
        if (i < N_EDGES) {
            int h = head[i];
            bkt[k] = h >> 10;
            rec[k] = ((h & 1023) << 22) | ((etype[i] - 1) << 18) | tail[i];
            rnk[k] = atomicAdd(&lh[bkt[k]], 1);
        }
    }
    __syncthreads();
    lbase[t] = lh[t] ? atomicAdd(&gcur[t], lh[t]) : 0;
    __syncthreads();
    #pragma unroll
    for (int k = 0; k < 16; ++k)
        if (rnk[k] >= 0) binbuf[lbase[bkt[k]] + rnk[k]] = rec[k];
}

__device__ void dev_bin_inter(int b, const int* __restrict__ rows,
                              const int* __restrict__ cols, const float* __restrict__ vals,
                              int* __restrict__ gcur, int2* __restrict__ binbuf) {
    __shared__ int lh[256], lbase[256];
    int t = threadIdx.x;
    lh[t] = 0; __syncthreads();
    int base = b * ACHUNK;
    int recx[16], recy[16], rnk[16], bkt[16];
    #pragma unroll
    for (int k = 0; k < 16; ++k) {
        int i = base + k * 256 + t;
        rnk[k] = -1; recx[k] = 0; recy[k] = 0; bkt[k] = 0;
        if (i < NNZ) {
            int r = rows[i];
            bkt[k] = r >> 10;
            recx[k] = ((r & 1023) << 18) | cols[i];
            recy[k] = __float_as_int(vals[i]);
            rnk[k] = atomicAdd(&lh[bkt[k]], 1);
        }
    }
    __syncthreads();
    lbase[t] = lh[t] ? atomicAdd(&gcur[t], lh[t]) : 0;
    __syncthreads();
    #pragma unroll
    for (int k = 0; k < 16; ++k)
        if (rnk[k] >= 0) {
            int2 p; p.x = recx[k]; p.y = recy[k];
            binbuf[lbase[bkt[k]] + rnk[k]] = p;
        }
}

__global__ __launch_bounds__(256) void bin_kernel(const int* __restrict__ head,
                                                  const int* __restrict__ tail,
                                                  const int* __restrict__ etype,
                                                  const int* __restrict__ rows,
                                                  const int* __restrict__ cols,
                                                  const float* __restrict__ vals,
                                                  int* __restrict__ gce, int* __restrict__ gcu,
                                                  int* __restrict__ bine, int2* __restrict__ binu) {
    int bid = blockIdx.x;
    if (bid < GA) dev_bin_edges(bid, head, tail, etype, gce, bine);
    else          dev_bin_inter(bid - GA, rows, cols, vals, gcu, binu);
}

// ============ kernel D: per-bucket CSR finalize + degree histogram ===========
__device__ void dev_build_e(int b, const int* __restrict__ bbase,
                            const int* __restrict__ binbuf,
                            int* __restrict__ eoff, int* __restrict__ epk,
                            int* __restrict__ dbinE) {
    __shared__ int lh[CB];
    __shared__ int ss[256];
    __shared__ int ldeg[64];
    int t = threadIdx.x;
    int bstart = bbase[b], bend = bbase[b + 1];
    #pragma unroll
    for (int k = 0; k < 4; ++k) lh[t * 4 + k] = 0;
    if (t < 64) ldeg[t] = 0;
    __syncthreads();
    for (int j = bstart + t; j < bend; j += 256)
        atomicAdd(&lh[(u32)binbuf[j] >> 22], 1);
    __syncthreads();
    int v[4], acc = 0;
    #pragma unroll
    for (int k = 0; k < 4; ++k) { v[k] = lh[t * 4 + k]; acc += v[k]; }
    ss[t] = acc; __syncthreads();
    #pragma unroll
    for (int d = 1; d < 256; d <<= 1) {
        int x = (t >= d) ? ss[t - d] : 0;
        __syncthreads();
        ss[t] += x;
        __syncthreads();
    }
    int excl = ss[t] - acc;
    int hbase = b * CB;
    #pragma unroll
    for (int k = 0; k < 4; ++k) {
        int hl = t * 4 + k;
        int h = hbase + hl;
        if (h < N_ENTITIES) {
            eoff[h] = bstart + excl;
            atomicAdd(&ldeg[63 - min(v[k], 63)], 1);   // descending-degree bins
        }
        lh[hl] = excl;
        excl += v[k];
    }
    __syncthreads();
    if (t < 64 && ldeg[t]) atomicAdd(&dbinE[t], ldeg[t]);
    for (int j = bstart + t; j < bend; j += 256) {
        int rec = binbuf[j];
        int pos = atomicAdd(&lh[(u32)rec >> 22], 1);
        epk[bstart + pos] = rec & 0x3FFFFF;   // rel<<18 | tail
    }
}

__device__ void dev_build_u(int b, const int* __restrict__ bbase,
                            const int2* __restrict__ binbuf,
                            int* __restrict__ uoff, int2* __restrict__ ucv,
                            int* __restrict__ dbinU) {
    __shared__ int lh[CB];
    __shared__ int ss[256];
    __shared__ int ldeg[64];
    int t = threadIdx.x;
    int bstart = bbase[b], bend = bbase[b + 1];
    #pragma unroll
    for (int k = 0; k < 4; ++k) lh[t * 4 + k] = 0;
    if (t < 64) ldeg[t] = 0;
    __syncthreads();
    for (int j = bstart + t; j < bend; j += 256)
        atomicAdd(&lh[(u32)binbuf[j].x >> 18], 1);
    __syncthreads();
    int v[4], acc = 0;
    #pragma unroll
    for (int k = 0; k < 4; ++k) { v[k] = lh[t * 4 + k]; acc += v[k]; }
    ss[t] = acc; __syncthreads();
    #pragma unroll
    for (int d = 1; d < 256; d <<= 1) {
        int x = (t >= d) ? ss[t - d] : 0;
        __syncthreads();
        ss[t] += x;
        __syncthreads();
    }
    int excl = ss[t] - acc;
    int ubase = b * CB;
    #pragma unroll
    for (int k = 0; k < 4; ++k) {
        int ul = t * 4 + k;
        int u = ubase + ul;
        if (u < N_USERS) {
            uoff[u] = bstart + excl;
            atomicAdd(&ldeg[63 - min(v[k], 63)], 1);
        }
        lh[ul] = excl;
        excl += v[k];
    }
    __syncthreads();
    if (t < 64 && ldeg[t]) atomicAdd(&dbinU[t], ldeg[t]);
    for (int j = bstart + t; j < bend; j += 256) {
        int2 rec = binbuf[j];
        int pos = atomicAdd(&lh[(u32)rec.x >> 18], 1);
        int2 out; out.x = rec.x & 0x3FFFF; out.y = rec.y;
        ucv[bstart + pos] = out;
    }
}

__global__ __launch_bounds__(256) void build_kernel(const int* __restrict__ bbe,
                                                    const int* __restrict__ bbu,
                                                    const int* __restrict__ bine,
                                                    const int2* __restrict__ binu,
                                                    int* __restrict__ eoff, int* __restrict__ epk,
                                                    int* __restrict__ uoff, int2* __restrict__ ucv,
                                                    int* __restrict__ dbinE, int* __restrict__ dbinU) {
    int bid = blockIdx.x;
    if (bid < NBE) dev_build_e(bid, bbe, bine, eoff, epk, dbinE);
    else           dev_build_u(bid - NBE, bbu, binu, uoff, ucv, dbinU);
}

// ============ kernel E: degree-bin scan (1 block) ============================
__global__ void deg_scan(const int* __restrict__ dbinE, const int* __restrict__ dbinU,
                         int* __restrict__ curE, int* __restrict__ curU) {
    int t = threadIdx.x;
    if (t == 0) { int run = 0; for (int b = 0; b < 64; ++b) { curE[b] = run; run += dbinE[b]; } }
    if (t == 1) { int run = 0; for (int b = 0; b < 64; ++b) { curU[b] = run; run += dbinU[b]; } }
}

// ============ kernel F: degree-sorted permutation ============================
__device__ void dev_perm(int b, int n, const int* __restrict__ off,
                         int* __restrict__ gcur, int2* __restrict__ perm) {
    __shared__ int lh[64], lbase[64];
    int t = threadIdx.x;
    if (t < 64) lh[t] = 0;
    __syncthreads();
    int base = b * PCHUNK;
    int rnk[16], bin[16], deg[16], st[16];
    #pragma unroll
    for (int k = 0; k < 16; ++k) {
        int i = base + k * 256 + t;
        rnk[k] = -1;
        if (i < n) {
            int s0 = off[i], s1 = off[i + 1];
            deg[k] = s1 - s0; st[k] = s0;
            bin[k] = 63 - min(deg[k], 63);     // descending degree
            rnk[k] = atomicAdd(&lh[bin[k]], 1);
        }
    }
    __syncthreads();
    if (t < 64) lbase[t] = lh[t] ? atomicAdd(&gcur[t], lh[t]) : 0;
    __syncthreads();
    #pragma unroll
    for (int k = 0; k < 16; ++k)
        if (rnk[k] >= 0) {
            int i = base + k * 256 + t;
            int2 p;
            p.x = (int)(((u32)min(deg[k], 16383) << 18) | (u32)i);
            p.y = st[k];
            perm[lbase[bin[k]] + rnk[k]] = p;
        }
}

__global__ __launch_bounds__(256) void perm_kernel(const int* __restrict__ eoff,
                                                   const int* __restrict__ uoff,
                                                   int* __restrict__ curE, int* __restrict__ curU,
                                                   int2* __restrict__ permE, int2* __restrict__ permU) {
    int bid = blockIdx.x;
    if (bid < GPE) dev_perm(bid, N_ENTITIES, eoff, curE, permE);
    else           dev_perm(bid - GPE, N_USERS, uoff, curU, permU);
}

// ============ hop kernels (kg + user merged), 4-deep pipelined gather ========
__device__ void dev_kg_hop(int widg, const u8* __restrict__ esrc,
                           const int2* __restrict__ permE,
                           const int* __restrict__ epk,
                           const float* __restrict__ weight,
                           const float* __restrict__ emb0,
                           u8* __restrict__ enew, float* __restrict__ eres, int last) {
    int lane = threadIdx.x & 63;
    int slot = lane >> 3, seg = lane & 7;
    int2 pe = permE[widg * 8 + slot];
    u32 px = (u32)pe.x;
    int d = px >> 18, h = (int)(px & 0x3FFFFu), s = pe.y;
    int dmax = d;
    dmax = max(dmax, __shfl_xor(dmax, 8, 64));
    dmax = max(dmax, __shfl_xor(dmax, 16, 64));
    dmax = max(dmax, __shfl_xor(dmax, 32, 64));

    float acc[8];
    #pragma unroll
    for (int k = 0; k < 8; ++k) acc[k] = 0.0f;
    const uint2 uz = make_uint2(0u, 0u);

    for (int it = 0; it < dmax; it += 4) {
        int p0 = (it     < d) ? epk[s + it]     : 0;
        int p1 = (it + 1 < d) ? epk[s + it + 1] : 0;
        int p2 = (it + 2 < d) ? epk[s + it + 2] : 0;
        int p3 = (it + 3 < d) ? epk[s + it + 3] : 0;
        uint2 rv0 = (it     < d) ? *(const uint2*)(esrc + (size_t)(p0 & 0x3FFFF) * CDIM + seg * 8) : uz;
        uint2 rv1 = (it + 1 < d) ? *(const uint2*)(esrc + (size_t)(p1 & 0x3FFFF) * CDIM + seg * 8) : uz;
        uint2 rv2 = (it + 2 < d) ? *(const uint2*)(esrc + (size_t)(p2 & 0x3FFFF) * CDIM + seg * 8) : uz;
        uint2 rv3 = (it + 3 < d) ? *(const uint2*)(esrc + (size_t)(p3 & 0x3FFFF) * CDIM + seg * 8) : uz;
        fma_rowW(acc, rv0, p0 >> 18, weight, seg);
        fma_rowW(acc, rv1, p1 >> 18, weight, seg);
        fma_rowW(acc, rv2, p2 >> 18, weight, seg);
        fma_rowW(acc, rv3, p3 >> 18, weight, seg);
    }
    float inv = 1.0f / fmaxf((float)d, 1.0f);
    float ssq = 0.0f;
    #pragma unroll
    for (int k = 0; k < 8; ++k) { acc[k] *= inv; ssq += acc[k] * acc[k]; }
    ssq += __shfl_xor(ssq, 1, 64);
    ssq += __shfl_xor(ssq, 2, 64);
    ssq += __shfl_xor(ssq, 4, 64);
    float rn = 1.0f / fmaxf(sqrtf(ssq), 1e-12f);
    #pragma unroll
    for (int k = 0; k < 8; ++k) acc[k] *= rn;

    size_t base = (size_t)h * CDIM + seg * 8;
    if (!last) {
        *(uint2*)(enew + base) = pack8_fp8(acc);
    } else {
        uint2 pv = *(const uint2*)(esrc + base);   // esrc == hop0 output eA (fp8)
        float o0[8]; unpack8_fp8(pv, o0);
        float4 a = *(const float4*)(emb0 + base);
        float4 b = *(const float4*)(emb0 + base + 4);
        float4 r0, r1;
        r0.x = a.x + o0[0] + acc[0]; r0.y = a.y + o0[1] + acc[1];
        r0.z = a.z + o0[2] + acc[2]; r0.w = a.w + o0[3] + acc[3];
        r1.x = b.x + o0[4] + acc[4]; r1.y = b.y + o0[5] + acc[5];
        r1.z = b.z + o0[6] + acc[6]; r1.w = b.w + o0[7] + acc[7];
        *(float4*)(eres + base) = r0;
        *(float4*)(eres + base + 4) = r1;
    }
}

__device__ void dev_user_hop(int widg, const float* __restrict__ uoldf,
                             const u16* __restrict__ uoldb,
                             const u8* __restrict__ esrc,
                             const int2* __restrict__ permU,
                             const int2* __restrict__ ucv,
                             const float* __restrict__ latent,
                             const float* __restrict__ dw,
                             const float* __restrict__ uemb0,
                             u16* __restrict__ unew, float* __restrict__ ures, int last) {
    int lane = threadIdx.x & 63;
    int slot = lane >> 3, seg = lane & 7;
    int2 pe = permU[widg * 8 + slot];
    u32 px = (u32)pe.x;
    int d = px >> 18, u = (int)(px & 0x3FFFFu), s = pe.y;
    int dmax = d;
    dmax = max(dmax, __shfl_xor(dmax, 8, 64));
    dmax = max(dmax, __shfl_xor(dmax, 16, 64));
    dmax = max(dmax, __shfl_xor(dmax, 32, 64));

    float acc[8];
    #pragma unroll
    for (int k = 0; k < 8; ++k) acc[k] = 0.0f;
    const uint2 uz = make_uint2(0u, 0u);
    const int2 cz = make_int2(0, 0);

    for (int it = 0; it < dmax; it += 4) {
        int2 c0 = (it     < d) ? ucv[s + it]     : cz;
        int2 c1 = (it + 1 < d) ? ucv[s + it + 1] : cz;
        int2 c2 = (it + 2 < d) ? ucv[s + it + 2] : cz;
        int2 c3 = (it + 3 < d) ? ucv[s + it + 3] : cz;
        uint2 rv0 = (it     < d) ? *(const uint2*)(esrc + (size_t)c0.x * CDIM + seg * 8) : uz;
        uint2 rv1 = (it + 1 < d) ? *(const uint2*)(esrc + (size_t)c1.x * CDIM + seg * 8) : uz;
        uint2 rv2 = (it + 2 < d) ? *(const uint2*)(esrc + (size_t)c2.x * CDIM + seg * 8) : uz;
        uint2 rv3 = (it + 3 < d) ? *(const uint2*)(esrc + (size_t)c3.x * CDIM + seg * 8) : uz;
        fma_rowV(acc, rv0, __int_as_float(c0.y));
        fma_rowV(acc, rv1, __int_as_float(c1.y));
        fma_rowV(acc, rv2, __int_as_float(c2.y));
        fma_rowV(acc, rv3, __int_as_float(c3.y));
    }

    float uo[8];
    size_t ubase = (size_t)u * CDIM + seg * 8;
    if (uoldb) {
        uint4 pv = *(const uint4*)(uoldb + ubase);
        unpack8_bf(pv, uo);
    } else {
        float4 a = *(const float4*)(uoldf + ubase);
        float4 b = *(const float4*)(uoldf + ubase + 4);
        uo[0] = a.x; uo[1] = a.y; uo[2] = a.z; uo[3] = a.w;
        uo[4] = b.x; uo[5] = b.y; uo[6] = b.z; uo[7] = b.w;
    }
    float dts[N_FACTORS];
    #pragma unroll
    for (int f = 0; f < N_FACTORS; ++f) {
        const float4* lp = (const float4*)(latent + f * CDIM + seg * 8);
        float4 l0 = lp[0], l1 = lp[1];
        float p = uo[0] * l0.x + uo[1] * l0.y + uo[2] * l0.z + uo[3] * l0.w +
                  uo[4] * l1.x + uo[5] * l1.y + uo[6] * l1.z + uo[7] * l1.w;
        p += __shfl_xor(p, 1, 64);
        p += __shfl_xor(p, 2, 64);
        p += __shfl_xor(p, 4, 64);
        dts[f] = p;
    }
    float m = fmaxf(fmaxf(dts[0], dts[1]), fmaxf(dts[2], dts[3]));
    float e0 = __expf(dts[0] - m), e1 = __expf(dts[1] - m);
    float e2 = __expf(dts[2] - m), e3 = __expf(dts[3] - m);
    float inv_ssum = 1.0f / (e0 + e1 + e2 + e3);
    e0 *= inv_ssum; e1 *= inv_ssum; e2 *= inv_ssum; e3 *= inv_ssum;

    const float4* d0p = (const float4*)(dw + 0 * CDIM + seg * 8);
    const float4* d1p = (const float4*)(dw + 1 * CDIM + seg * 8);
    const float4* d2p = (const float4*)(dw + 2 * CDIM + seg * 8);
    const float4* d3p = (const float4*)(dw + 3 * CDIM + seg * 8);
    float4 ga0 = d0p[0], ga1 = d0p[1];
    float4 gb0 = d1p[0], gb1 = d1p[1];
    float4 gc0 = d2p[0], gc1 = d2p[1];
    float4 gd0 = d3p[0], gd1 = d3p[1];
    float g[8];
    g[0] = e0 * ga0.x + e1 * gb0.x + e2 * gc0.x + e3 * gd0.x;
    g[1] = e0 * ga0.y + e1 * gb0.y + e2 * gc0.y + e3 * gd0.y;
    g[2] = e0 * ga0.z + e1 * gb0.z + e2 * gc0.z + e3 * gd0.z;
    g[3] = e0 * ga0.w + e1 * gb0.w + e2 * gc0.w + e3 * gd0.w;
    g[4] = e0 * ga1.x + e1 * gb1.x + e2 * gc1.x + e3 * gd1.x;
    g[5] = e0 * ga1.y + e1 * gb1.y + e2 * gc1.y + e3 * gd1.y;
    g[6] = e0 * ga1.z + e1 * gb1.z + e2 * gc1.z + e3 * gd1.z;
    g[7] = e0 * ga1.w + e1 * gb1.w + e2 * gc1.w + e3 * gd1.w;

    float ssq = 0.0f;
    #pragma unroll
    for (int k = 0; k < 8; ++k) {
        acc[k] = acc[k] * (1.0f + g[k]);
        ssq += acc[k] * acc[k];
    }
    ssq += __shfl_xor(ssq, 1, 64);
    ssq += __shfl_xor(ssq, 2, 64);
    ssq += __shfl_xor(ssq, 4, 64);
    float rn = 1.0f / fmaxf(sqrtf(ssq), 1e-12f);
    #pragma unroll
    for (int k = 0; k < 8; ++k) acc[k] *= rn;

    if (!last) {
        *(uint4*)(unew + ubase) = pack8_bf(acc);
    } else {
        float4 a = *(const float4*)(uemb0 + ubase);
        float4 b = *(const float4*)(uemb0 + ubase + 4);
        float4 r0, r1;
        r0.x = a.x + uo[0] + acc[0]; r0.y = a.y + uo[1] + acc[1];
        r0.z = a.z + uo[2] + acc[2]; r0.w = a.w + uo[3] + acc[3];
        r1.x = b.x + uo[4] + acc[4]; r1.y = b.y + uo[5] + acc[5];
        r1.z = b.z + uo[6] + acc[6]; r1.w = b.w + uo[7] + acc[7];
        *(float4*)(ures + ubase) = r0;
        *(float4*)(ures + ubase + 4) = r1;
    }
}

__global__ __launch_bounds__(256) void hop_kernel(const u8* __restrict__ e_src,
                                                  const int2* __restrict__ permE,
                                                  const int* __restrict__ epk,
                                                  const float* __restrict__ weight,
                                                  const float* __restrict__ entity_emb,
                                                  u8* __restrict__ eA,
                                                  float* __restrict__ eres,
                                                  const float* __restrict__ uoldf,
                                                  const u16* __restrict__ uoldb,
                                                  const int2* __restrict__ permU,
                                                  const int2* __restrict__ ucv,
                                                  const float* __restrict__ latent,
                                                  const float* __restrict__ dw,
                                                  const float* __restrict__ user_emb,
                                                  u16* __restrict__ uA,
                                                  float* __restrict__ ures,
                                                  int last) {
    int bid = blockIdx.x;
    int wave = threadIdx.x >> 6;
    if (bid < KG_BLOCKS) {
        dev_kg_hop(bid * 4 + wave, e_src, permE, epk, weight, entity_emb, eA, eres, last);
    } else {
        dev_user_hop((bid - KG_BLOCKS) * 4 + wave, uoldf, uoldb, e_src, permU, ucv,
                     latent, dw, user_emb, uA, ures, last);
    }
}

static inline size_t align16(size_t x) { return (x + 15) & ~(size_t)15; }

extern "C" void kernel_launch(void* const* d_in, const int* in_sizes, int n_in,
                              void* d_out, int out_size, void* d_ws, size_t ws_size,
                              hipStream_t stream) {
    const float* user_emb   = (const float*)d_in[0];
    const float* entity_emb = (const float*)d_in[1];
    const float* latent_emb = (const float*)d_in[2];
    const float* weight     = (const float*)d_in[3];
    const float* att        = (const float*)d_in[4];
    const int*   edge_index = (const int*)d_in[5];
    const int*   edge_type  = (const int*)d_in[6];
    const int*   inter_rows = (const int*)d_in[7];
    const int*   inter_cols = (const int*)d_in[8];
    const float* inter_vals = (const float*)d_in[9];

    float* eres = (float*)d_out;
    float* ures = eres + (size_t)N_ENTITIES * CDIM;
    float* cor  = ures + (size_t)N_USERS * CDIM;

    char* ws = (char*)d_ws;
    u8*    ef8   = (u8*)ws;   ws += align16(sizeof(u8) * (size_t)N_ENTITIES * CDIM);
    u8*    eA    = (u8*)ws;   ws += align16(sizeof(u8) * (size_t)N_ENTITIES * CDIM);
    u16*   uA    = (u16*)ws;  ws += align16(sizeof(u16) * (size_t)N_USERS * CDIM);
    int*   eoff  = (int*)ws;  ws += align16(sizeof(int) * (N_ENTITIES + 1));
    int*   epk   = (int*)ws;  ws += align16(sizeof(int) * N_EDGES);
    int*   uoff  = (int*)ws;  ws += align16(sizeof(int) * (N_USERS + 1));
    int2*  ucv   = (int2*)ws; ws += align16(sizeof(int2) * NNZ);
    int*   bine  = (int*)ws;  ws += align16(sizeof(int) * N_EDGES);
    int2*  binu  = (int2*)ws; ws += align16(sizeof(int2) * NNZ);
    int*   ctrs  = (int*)ws;  ws += align16(sizeof(int) * 640);   // bhe256|bhu256|dbinE64|dbinU64
    int*   bbe   = (int*)ws;  ws += align16(sizeof(int) * 257);
    int*   bbu   = (int*)ws;  ws += align16(sizeof(int) * 257);
    int*   gce   = (int*)ws;  ws += align16(sizeof(int) * 256);
    int*   gcu   = (int*)ws;  ws += align16(sizeof(int) * 256);
    int*   curE  = (int*)ws;  ws += align16(sizeof(int) * 64);
    int*   curU  = (int*)ws;  ws += align16(sizeof(int) * 64);
    int2*  permE = (int2*)ws; ws += align16(sizeof(int2) * N_ENTITIES);
    int2*  permU = (int2*)ws; ws += align16(sizeof(int2) * N_USERS);
    float* dw    = (float*)ws; ws += align16(sizeof(float) * N_FACTORS * CDIM);

    int* bhe   = ctrs;
    int* bhu   = ctrs + 256;
    int* dbinE = ctrs + 512;
    int* dbinU = ctrs + 576;

    const int* head = edge_index;
    const int* tail = edge_index + N_EDGES;

    (void)hipMemsetAsync(ctrs, 0, sizeof(int) * 640, stream);

    prep_kernel<<<GCVT + 2 * GA + 1, 256, 0, stream>>>(entity_emb, ef8, head, inter_rows,
                                                       bhe, bhu, att, weight, dw, cor);
    bucket_scan2<<<2, 256, 0, stream>>>(bhe, bhu, bbe, bbu, gce, gcu,
                                        eoff + N_ENTITIES, uoff + N_USERS);
    bin_kernel<<<2 * GA, 256, 0, stream>>>(head, tail, edge_type,
                                           inter_rows, inter_cols, inter_vals,
                                           gce, gcu, bine, binu);
    build_kernel<<<NBE + NBU, 256, 0, stream>>>(bbe, bbu, bine, binu,
                                                eoff, epk, uoff, ucv, dbinE, dbinU);
    deg_scan<<<1, 64, 0, stream>>>(dbinE, dbinU, curE, curU);
    perm_kernel<<<GPE + GPU_, 256, 0, stream>>>(eoff, uoff, curE, curU, permE, permU);

    // hop 0: gather from ef8; write fp8 eA + bf16 uA
    hop_kernel<<<KG_BLOCKS + USER_BLOCKS, 256, 0, stream>>>(
        ef8, permE, epk, weight, entity_emb, eA, eres,
        user_emb, (const u16*)nullptr, permU, ucv, latent_emb, dw, user_emb, uA, ures, 0);
    // hop 1: gather from eA; write res = emb0 + o0 + o1
    hop_kernel<<<KG_BLOCKS + USER_BLOCKS, 256, 0, stream>>>(
        eA, permE, epk, weight, entity_emb, (u8*)nullptr, eres,
        (const float*)nullptr, uA, permU, ucv, latent_emb, dw, user_emb, (u16*)nullptr, ures, 1);
}